// Round 1
// baseline (2399.528 us; speedup 1.0000x reference)
//
#include <hip/hip_runtime.h>
#include <hip/hip_bf16.h>

// Problem constants (derived from in_sizes at launch as well)
// N=50000 nodes, E=800000 edges, Q=200000 queries, d_in=64, h=128

__global__ __launch_bounds__(256) void k_zero(float* __restrict__ p, int n) {
    int i = blockIdx.x * 256 + threadIdx.x;
    if (i < n) p[i] = 0.0f;
}

__global__ __launch_bounds__(256) void k_deg(const int* __restrict__ row,
                                             float* __restrict__ deg, int E) {
    int i = blockIdx.x * 256 + threadIdx.x;
    if (i < E) atomicAdd(&deg[row[i]], 1.0f);
}

// dis[i] = (deg[i]+1)^-0.5 ; agg1[i][:] = x[i][:] * dis[i]^2  (self-loop term)
__global__ __launch_bounds__(256) void k_dis_init(const float* __restrict__ x,
                                                  const float* __restrict__ deg,
                                                  float* __restrict__ dis,
                                                  float* __restrict__ agg1, int N) {
    int tid = blockIdx.x * 256 + threadIdx.x;
    int node = tid >> 4;
    if (node >= N) return;
    int c = tid & 15;  // float4 chunk of 64
    float d = 1.0f / sqrtf(deg[node] + 1.0f);
    if (c == 0) dis[node] = d;
    float dd = d * d;
    float4 v = *(const float4*)(x + (size_t)node * 64 + c * 4);
    v.x *= dd; v.y *= dd; v.z *= dd; v.w *= dd;
    *(float4*)(agg1 + (size_t)node * 64 + c * 4) = v;
}

// scatter: agg[col[e]] += src[row[e]] * dis[row]*dis[col], D = 4<<LOGCH floats
template <int LOGCH>
__global__ __launch_bounds__(256) void k_scatter(const float* __restrict__ src,
                                                 const int* __restrict__ row,
                                                 const int* __restrict__ col,
                                                 const float* __restrict__ dis,
                                                 float* __restrict__ agg, int E) {
    int tid = blockIdx.x * 256 + threadIdx.x;
    int e = tid >> LOGCH;
    if (e >= E) return;
    int c = tid & ((1 << LOGCH) - 1);
    const int D = 4 << LOGCH;
    int r = row[e], cc = col[e];
    float nrm = dis[r] * dis[cc];
    float4 v = *(const float4*)(src + (size_t)r * D + c * 4);
    float* dst = agg + (size_t)cc * D + c * 4;
    atomicAdd(dst + 0, v.x * nrm);
    atomicAdd(dst + 1, v.y * nrm);
    atomicAdd(dst + 2, v.z * nrm);
    atomicAdd(dst + 3, v.w * nrm);
}

// out = act(A[N,K] @ W[K,128] + b); optionally agg[i] = out[i]*dis[i]^2
template <int K, bool RELU, bool WRITE_AGG>
__global__ __launch_bounds__(256) void k_gemm(const float* __restrict__ A,
                                              const float* __restrict__ W,
                                              const float* __restrict__ b,
                                              const float* __restrict__ dis,
                                              float* __restrict__ out,
                                              float* __restrict__ agg, int N) {
    __shared__ float As[32][33];   // [row][kk] padded
    __shared__ float Ws[32][128];  // [kk][j]
    int t = threadIdx.x;
    int rowBase = blockIdx.x * 32;
    int jg = t & 31;  // cols jg*4 .. +3
    int rg = t >> 5;  // rows rg*4 .. +3
    float acc[4][4] = {};
    for (int kc = 0; kc < K; kc += 32) {
        {
            int r = t >> 3;
            int kk4 = (t & 7) << 2;
            int gr = rowBase + r;
            float4 v = make_float4(0.f, 0.f, 0.f, 0.f);
            if (gr < N) v = *(const float4*)(A + (size_t)gr * K + kc + kk4);
            As[r][kk4 + 0] = v.x; As[r][kk4 + 1] = v.y;
            As[r][kk4 + 2] = v.z; As[r][kk4 + 3] = v.w;
        }
        {
            const float4* Wg = (const float4*)(W + (size_t)kc * 128);
            float4* Wl = (float4*)(&Ws[0][0]);
            Wl[t] = Wg[t];
            Wl[t + 256] = Wg[t + 256];
            Wl[t + 512] = Wg[t + 512];
            Wl[t + 768] = Wg[t + 768];
        }
        __syncthreads();
#pragma unroll
        for (int kk = 0; kk < 32; kk++) {
            float a0 = As[rg * 4 + 0][kk];
            float a1 = As[rg * 4 + 1][kk];
            float a2 = As[rg * 4 + 2][kk];
            float a3 = As[rg * 4 + 3][kk];
            float4 w = *(const float4*)(&Ws[kk][jg * 4]);
            acc[0][0] += a0 * w.x; acc[0][1] += a0 * w.y; acc[0][2] += a0 * w.z; acc[0][3] += a0 * w.w;
            acc[1][0] += a1 * w.x; acc[1][1] += a1 * w.y; acc[1][2] += a1 * w.z; acc[1][3] += a1 * w.w;
            acc[2][0] += a2 * w.x; acc[2][1] += a2 * w.y; acc[2][2] += a2 * w.z; acc[2][3] += a2 * w.w;
            acc[3][0] += a3 * w.x; acc[3][1] += a3 * w.y; acc[3][2] += a3 * w.z; acc[3][3] += a3 * w.w;
        }
        __syncthreads();
    }
#pragma unroll
    for (int i = 0; i < 4; i++) {
        int r = rowBase + rg * 4 + i;
        if (r >= N) continue;
        float d2 = 0.f;
        if (WRITE_AGG) { float d = dis[r]; d2 = d * d; }
        int j = jg * 4;
        float4 bv = *(const float4*)(b + j);
        float4 v;
        v.x = acc[i][0] + bv.x; v.y = acc[i][1] + bv.y;
        v.z = acc[i][2] + bv.z; v.w = acc[i][3] + bv.w;
        if (RELU) {
            v.x = fmaxf(v.x, 0.f); v.y = fmaxf(v.y, 0.f);
            v.z = fmaxf(v.z, 0.f); v.w = fmaxf(v.w, 0.f);
        }
        *(float4*)(out + (size_t)r * 128 + j) = v;
        if (WRITE_AGG) {
            float4 a2v;
            a2v.x = v.x * d2; a2v.y = v.y * d2; a2v.z = v.z * d2; a2v.w = v.w * d2;
            *(float4*)(agg + (size_t)r * 128 + j) = a2v;
        }
    }
}

// query head: out[q] = relu(cat(h2[src],h2[dst]) @ Wc1 + bc1) @ Wc2 + bc2
__global__ __launch_bounds__(256) void k_query(const float* __restrict__ h2,
                                               const int* __restrict__ srcA,
                                               const int* __restrict__ dstA,
                                               const float* __restrict__ Wc1,
                                               const float* __restrict__ bc1,
                                               const float* __restrict__ Wc2,
                                               const float* __restrict__ bc2,
                                               float* __restrict__ out, int Q) {
    __shared__ float As[32][33];   // cat chunk [q][kk]
    __shared__ float Ws[32][128];  // Wc1 chunk
    __shared__ float red[32][33];  // per-q, per-jg partials
    int t = threadIdx.x;
    int qBase = blockIdx.x * 32;
    int jg = t & 31;
    int rg = t >> 5;
    float acc[4][4] = {};
    for (int kc = 0; kc < 256; kc += 32) {
        {
            int q = t >> 3;
            int kk4 = (t & 7) << 2;
            int k = kc + kk4;
            int node = (k < 128) ? srcA[qBase + q] : dstA[qBase + q];
            float4 v = *(const float4*)(h2 + (size_t)node * 128 + (k & 127));
            As[q][kk4 + 0] = v.x; As[q][kk4 + 1] = v.y;
            As[q][kk4 + 2] = v.z; As[q][kk4 + 3] = v.w;
        }
        {
            const float4* Wg = (const float4*)(Wc1 + (size_t)kc * 128);
            float4* Wl = (float4*)(&Ws[0][0]);
            Wl[t] = Wg[t];
            Wl[t + 256] = Wg[t + 256];
            Wl[t + 512] = Wg[t + 512];
            Wl[t + 768] = Wg[t + 768];
        }
        __syncthreads();
#pragma unroll
        for (int kk = 0; kk < 32; kk++) {
            float a0 = As[rg * 4 + 0][kk];
            float a1 = As[rg * 4 + 1][kk];
            float a2 = As[rg * 4 + 2][kk];
            float a3 = As[rg * 4 + 3][kk];
            float4 w = *(const float4*)(&Ws[kk][jg * 4]);
            acc[0][0] += a0 * w.x; acc[0][1] += a0 * w.y; acc[0][2] += a0 * w.z; acc[0][3] += a0 * w.w;
            acc[1][0] += a1 * w.x; acc[1][1] += a1 * w.y; acc[1][2] += a1 * w.z; acc[1][3] += a1 * w.w;
            acc[2][0] += a2 * w.x; acc[2][1] += a2 * w.y; acc[2][2] += a2 * w.z; acc[2][3] += a2 * w.w;
            acc[3][0] += a3 * w.x; acc[3][1] += a3 * w.y; acc[3][2] += a3 * w.z; acc[3][3] += a3 * w.w;
        }
        __syncthreads();
    }
    int j = jg * 4;
    float4 bv = *(const float4*)(bc1 + j);
    float4 w2 = *(const float4*)(Wc2 + j);
#pragma unroll
    for (int i = 0; i < 4; i++) {
        float z0 = fmaxf(acc[i][0] + bv.x, 0.f);
        float z1 = fmaxf(acc[i][1] + bv.y, 0.f);
        float z2 = fmaxf(acc[i][2] + bv.z, 0.f);
        float z3 = fmaxf(acc[i][3] + bv.w, 0.f);
        red[rg * 4 + i][jg] = z0 * w2.x + z1 * w2.y + z2 * w2.z + z3 * w2.w;
    }
    __syncthreads();
    if (t < 32) {
        float s = bc2[0];
#pragma unroll 8
        for (int g = 0; g < 32; g++) s += red[t][g];
        out[qBase + t] = s;
    }
}

extern "C" void kernel_launch(void* const* d_in, const int* in_sizes, int n_in,
                              void* d_out, int out_size, void* d_ws, size_t ws_size,
                              hipStream_t stream) {
    const float* x   = (const float*)d_in[0];
    const int*   ei  = (const int*)d_in[1];
    const int*   eli = (const int*)d_in[2];
    const float* W1  = (const float*)d_in[3];
    const float* b1  = (const float*)d_in[4];
    const float* W2  = (const float*)d_in[5];
    const float* b2  = (const float*)d_in[6];
    const float* Wc1 = (const float*)d_in[7];
    const float* bc1 = (const float*)d_in[8];
    const float* Wc2 = (const float*)d_in[9];
    const float* bc2 = (const float*)d_in[10];
    float* out = (float*)d_out;
    float* ws = (float*)d_ws;

    const int N = in_sizes[0] / 64;
    const int E = in_sizes[1] / 2;
    const int Q = in_sizes[2] / 2;

    // workspace layout (floats)
    float* deg  = ws;               // N
    float* dis  = ws + 65536;       // N
    float* agg1 = ws + 131072;      // N*64
    float* h1   = ws + 3331072;     // N*128
    float* agg2 = ws + 9731072;     // N*128
    float* h2   = ws + 16131072;    // N*128

    const int* row = ei;        // edge_index[0]
    const int* col = ei + E;    // edge_index[1]
    const int* srcA = eli;      // edge_label_index[0]
    const int* dstA = eli + Q;  // edge_label_index[1]

    // 1. zero degrees
    k_zero<<<(N + 255) / 256, 256, 0, stream>>>(deg, N);
    // 2. degrees (over row only; self loop folded in as +1 later)
    k_deg<<<(E + 255) / 256, 256, 0, stream>>>(row, deg, E);
    // 3. dis + agg1 self-loop init
    k_dis_init<<<(N * 16 + 255) / 256, 256, 0, stream>>>(x, deg, dis, agg1, N);
    // 4. conv1 scatter (d=64)
    k_scatter<4><<<((size_t)E * 16 + 255) / 256, 256, 0, stream>>>(x, row, col, dis, agg1, E);
    // 5. h1 = relu(agg1 @ W1 + b1); agg2 = h1 * dis^2 (self-loop init for conv2)
    k_gemm<64, true, true><<<(N + 31) / 32, 256, 0, stream>>>(agg1, W1, b1, dis, h1, agg2, N);
    // 6. conv2 scatter (d=128)
    k_scatter<5><<<((size_t)E * 32 + 255) / 256, 256, 0, stream>>>(h1, row, col, dis, agg2, E);
    // 7. h2 = agg2 @ W2 + b2
    k_gemm<128, false, false><<<(N + 31) / 32, 256, 0, stream>>>(agg2, W2, b2, nullptr, h2, nullptr, N);
    // 8. query head
    k_query<<<(Q + 31) / 32, 256, 0, stream>>>(h2, srcA, dstA, Wc1, bc1, Wc2, bc2, out, Q);
}

// Round 2
// 547.951 us; speedup vs baseline: 4.3791x; 4.3791x over previous
//
#include <hip/hip_runtime.h>
#include <hip/hip_bf16.h>

// N=50000 nodes, E=800000 edges, Q=200000 queries, d_in=64, h=128
// Strategy: CSR-by-destination + gather (no feature atomics).
// agg[i] = dis[i] * (s[i] + sum_{e: col[e]==i} s[row[e]])  where s = feat*dis.

__global__ __launch_bounds__(256) void k_zero_i(int* __restrict__ p, int n) {
    int i = blockIdx.x * 256 + threadIdx.x;
    if (i < n) p[i] = 0;
}

__global__ __launch_bounds__(256) void k_count(const int* __restrict__ row,
                                               const int* __restrict__ col,
                                               int* __restrict__ cntRow,
                                               int* __restrict__ cntCol, int E) {
    int i = blockIdx.x * 256 + threadIdx.x;
    if (i < E) {
        atomicAdd(&cntRow[row[i]], 1);
        atomicAdd(&cntCol[col[i]], 1);
    }
}

__global__ __launch_bounds__(256) void k_dis(const int* __restrict__ cntRow,
                                             float* __restrict__ dis, int N) {
    int i = blockIdx.x * 256 + threadIdx.x;
    if (i < N) dis[i] = 1.0f / sqrtf((float)(cntRow[i] + 1));
}

// --- 3-kernel exclusive scan over cntCol (1024 elements per block) ---
__global__ __launch_bounds__(256) void k_scan1(const int* __restrict__ cnt,
                                               int* __restrict__ offs,
                                               int* __restrict__ bsum, int N) {
    __shared__ int ts[256];
    int t = threadIdx.x;
    int base = blockIdx.x * 1024 + t * 4;
    int v0 = (base + 0 < N) ? cnt[base + 0] : 0;
    int v1 = (base + 1 < N) ? cnt[base + 1] : 0;
    int v2 = (base + 2 < N) ? cnt[base + 2] : 0;
    int v3 = (base + 3 < N) ? cnt[base + 3] : 0;
    int sum = v0 + v1 + v2 + v3;
    ts[t] = sum;
    __syncthreads();
    for (int off = 1; off < 256; off <<= 1) {
        int x = (t >= off) ? ts[t - off] : 0;
        __syncthreads();
        ts[t] += x;
        __syncthreads();
    }
    int e = ts[t] - sum;  // exclusive
    if (base + 0 < N) offs[base + 0] = e;
    if (base + 1 < N) offs[base + 1] = e + v0;
    if (base + 2 < N) offs[base + 2] = e + v0 + v1;
    if (base + 3 < N) offs[base + 3] = e + v0 + v1 + v2;
    if (t == 255) bsum[blockIdx.x] = ts[255];
}

__global__ __launch_bounds__(256) void k_scan2(int* __restrict__ bsum, int B) {
    __shared__ int ts[256];
    int t = threadIdx.x;
    int v = (t < B) ? bsum[t] : 0;
    ts[t] = v;
    __syncthreads();
    for (int off = 1; off < 256; off <<= 1) {
        int x = (t >= off) ? ts[t - off] : 0;
        __syncthreads();
        ts[t] += x;
        __syncthreads();
    }
    if (t < B) bsum[t] = ts[t] - v;  // exclusive
}

__global__ __launch_bounds__(256) void k_scan3(int* __restrict__ offs,
                                               int* __restrict__ cursor,
                                               const int* __restrict__ bsum,
                                               int N, int E) {
    int i = blockIdx.x * 256 + threadIdx.x;
    if (i < N) {
        int o = offs[i] + bsum[i >> 10];
        offs[i] = o;
        cursor[i] = o;
    }
    if (i == 0) offs[N] = E;
}

__global__ __launch_bounds__(256) void k_fill(const int* __restrict__ row,
                                              const int* __restrict__ col,
                                              int* __restrict__ cursor,
                                              int* __restrict__ srcSorted, int E) {
    int e = blockIdx.x * 256 + threadIdx.x;
    if (e < E) {
        int c = col[e];
        int pos = atomicAdd(&cursor[c], 1);
        srcSorted[pos] = row[e];
    }
}

// xs = x * dis (pre-scale rows), d=64
__global__ __launch_bounds__(256) void k_xs(const float* __restrict__ x,
                                            const float* __restrict__ dis,
                                            float* __restrict__ xs, int N) {
    int tid = blockIdx.x * 256 + threadIdx.x;
    int node = tid >> 4;
    if (node >= N) return;
    int c4 = (tid & 15) * 4;
    float d = dis[node];
    float4 v = *(const float4*)(x + (size_t)node * 64 + c4);
    v.x *= d; v.y *= d; v.z *= d; v.w *= d;
    *(float4*)(xs + (size_t)node * 64 + c4) = v;
}

// agg[n] = dis[n] * (s[n] + sum_{e in CSR[n]} s[src_e]); D = 4<<LOGCH
template <int LOGCH>
__global__ __launch_bounds__(256) void k_gather(const float* __restrict__ s,
                                                const int* __restrict__ offs,
                                                const int* __restrict__ srcs,
                                                const float* __restrict__ dis,
                                                float* __restrict__ agg, int N) {
    int tid = blockIdx.x * 256 + threadIdx.x;
    int node = tid >> LOGCH;
    if (node >= N) return;
    int c4 = (tid & ((1 << LOGCH) - 1)) * 4;
    const int D = 4 << LOGCH;
    int e = offs[node], eEnd = offs[node + 1];
    float4 acc = *(const float4*)(s + (size_t)node * D + c4);  // self term
    int srcNext = (e < eEnd) ? srcs[e] : 0;
    while (e < eEnd) {
        int src = srcNext;
        e++;
        srcNext = (e < eEnd) ? srcs[e] : 0;
        float4 v = *(const float4*)(s + (size_t)src * D + c4);
        acc.x += v.x; acc.y += v.y; acc.z += v.z; acc.w += v.w;
    }
    float dn = dis[node];
    acc.x *= dn; acc.y *= dn; acc.z *= dn; acc.w *= dn;
    *(float4*)(agg + (size_t)node * D + c4) = acc;
}

// out = act(A[N,K] @ W[K,128] + b) * (SCALE ? dis : 1)
template <int K, bool RELU, bool SCALE>
__global__ __launch_bounds__(256) void k_gemm(const float* __restrict__ A,
                                              const float* __restrict__ W,
                                              const float* __restrict__ b,
                                              const float* __restrict__ dis,
                                              float* __restrict__ out, int N) {
    __shared__ float As[32][33];
    __shared__ float Ws[32][128];
    int t = threadIdx.x;
    int rowBase = blockIdx.x * 32;
    int jg = t & 31;
    int rg = t >> 5;
    float acc[4][4] = {};
    for (int kc = 0; kc < K; kc += 32) {
        {
            int r = t >> 3;
            int kk4 = (t & 7) << 2;
            int gr = rowBase + r;
            float4 v = make_float4(0.f, 0.f, 0.f, 0.f);
            if (gr < N) v = *(const float4*)(A + (size_t)gr * K + kc + kk4);
            As[r][kk4 + 0] = v.x; As[r][kk4 + 1] = v.y;
            As[r][kk4 + 2] = v.z; As[r][kk4 + 3] = v.w;
        }
        {
            const float4* Wg = (const float4*)(W + (size_t)kc * 128);
            float4* Wl = (float4*)(&Ws[0][0]);
            Wl[t] = Wg[t];
            Wl[t + 256] = Wg[t + 256];
            Wl[t + 512] = Wg[t + 512];
            Wl[t + 768] = Wg[t + 768];
        }
        __syncthreads();
#pragma unroll
        for (int kk = 0; kk < 32; kk++) {
            float a0 = As[rg * 4 + 0][kk];
            float a1 = As[rg * 4 + 1][kk];
            float a2 = As[rg * 4 + 2][kk];
            float a3 = As[rg * 4 + 3][kk];
            float4 w = *(const float4*)(&Ws[kk][jg * 4]);
            acc[0][0] += a0 * w.x; acc[0][1] += a0 * w.y; acc[0][2] += a0 * w.z; acc[0][3] += a0 * w.w;
            acc[1][0] += a1 * w.x; acc[1][1] += a1 * w.y; acc[1][2] += a1 * w.z; acc[1][3] += a1 * w.w;
            acc[2][0] += a2 * w.x; acc[2][1] += a2 * w.y; acc[2][2] += a2 * w.z; acc[2][3] += a2 * w.w;
            acc[3][0] += a3 * w.x; acc[3][1] += a3 * w.y; acc[3][2] += a3 * w.z; acc[3][3] += a3 * w.w;
        }
        __syncthreads();
    }
#pragma unroll
    for (int i = 0; i < 4; i++) {
        int r = rowBase + rg * 4 + i;
        if (r >= N) continue;
        float sc = SCALE ? dis[r] : 1.0f;
        int j = jg * 4;
        float4 bv = *(const float4*)(b + j);
        float4 v;
        v.x = acc[i][0] + bv.x; v.y = acc[i][1] + bv.y;
        v.z = acc[i][2] + bv.z; v.w = acc[i][3] + bv.w;
        if (RELU) {
            v.x = fmaxf(v.x, 0.f); v.y = fmaxf(v.y, 0.f);
            v.z = fmaxf(v.z, 0.f); v.w = fmaxf(v.w, 0.f);
        }
        if (SCALE) { v.x *= sc; v.y *= sc; v.z *= sc; v.w *= sc; }
        *(float4*)(out + (size_t)r * 128 + j) = v;
    }
}

// query head: out[q] = relu(cat(h2[src],h2[dst]) @ Wc1 + bc1) @ Wc2 + bc2
__global__ __launch_bounds__(256) void k_query(const float* __restrict__ h2,
                                               const int* __restrict__ srcA,
                                               const int* __restrict__ dstA,
                                               const float* __restrict__ Wc1,
                                               const float* __restrict__ bc1,
                                               const float* __restrict__ Wc2,
                                               const float* __restrict__ bc2,
                                               float* __restrict__ out, int Q) {
    __shared__ float As[32][33];
    __shared__ float Ws[32][128];
    __shared__ float red[32][33];
    int t = threadIdx.x;
    int qBase = blockIdx.x * 32;
    int jg = t & 31;
    int rg = t >> 5;
    float acc[4][4] = {};
    for (int kc = 0; kc < 256; kc += 32) {
        {
            int q = t >> 3;
            int kk4 = (t & 7) << 2;
            int k = kc + kk4;
            int node = (k < 128) ? srcA[qBase + q] : dstA[qBase + q];
            float4 v = *(const float4*)(h2 + (size_t)node * 128 + (k & 127));
            As[q][kk4 + 0] = v.x; As[q][kk4 + 1] = v.y;
            As[q][kk4 + 2] = v.z; As[q][kk4 + 3] = v.w;
        }
        {
            const float4* Wg = (const float4*)(Wc1 + (size_t)kc * 128);
            float4* Wl = (float4*)(&Ws[0][0]);
            Wl[t] = Wg[t];
            Wl[t + 256] = Wg[t + 256];
            Wl[t + 512] = Wg[t + 512];
            Wl[t + 768] = Wg[t + 768];
        }
        __syncthreads();
#pragma unroll
        for (int kk = 0; kk < 32; kk++) {
            float a0 = As[rg * 4 + 0][kk];
            float a1 = As[rg * 4 + 1][kk];
            float a2 = As[rg * 4 + 2][kk];
            float a3 = As[rg * 4 + 3][kk];
            float4 w = *(const float4*)(&Ws[kk][jg * 4]);
            acc[0][0] += a0 * w.x; acc[0][1] += a0 * w.y; acc[0][2] += a0 * w.z; acc[0][3] += a0 * w.w;
            acc[1][0] += a1 * w.x; acc[1][1] += a1 * w.y; acc[1][2] += a1 * w.z; acc[1][3] += a1 * w.w;
            acc[2][0] += a2 * w.x; acc[2][1] += a2 * w.y; acc[2][2] += a2 * w.z; acc[2][3] += a2 * w.w;
            acc[3][0] += a3 * w.x; acc[3][1] += a3 * w.y; acc[3][2] += a3 * w.z; acc[3][3] += a3 * w.w;
        }
        __syncthreads();
    }
    int j = jg * 4;
    float4 bv = *(const float4*)(bc1 + j);
    float4 w2 = *(const float4*)(Wc2 + j);
#pragma unroll
    for (int i = 0; i < 4; i++) {
        float z0 = fmaxf(acc[i][0] + bv.x, 0.f);
        float z1 = fmaxf(acc[i][1] + bv.y, 0.f);
        float z2 = fmaxf(acc[i][2] + bv.z, 0.f);
        float z3 = fmaxf(acc[i][3] + bv.w, 0.f);
        red[rg * 4 + i][jg] = z0 * w2.x + z1 * w2.y + z2 * w2.z + z3 * w2.w;
    }
    __syncthreads();
    if (t < 32) {
        float s = bc2[0];
#pragma unroll 8
        for (int g = 0; g < 32; g++) s += red[t][g];
        out[qBase + t] = s;
    }
}

extern "C" void kernel_launch(void* const* d_in, const int* in_sizes, int n_in,
                              void* d_out, int out_size, void* d_ws, size_t ws_size,
                              hipStream_t stream) {
    const float* x   = (const float*)d_in[0];
    const int*   ei  = (const int*)d_in[1];
    const int*   eli = (const int*)d_in[2];
    const float* W1  = (const float*)d_in[3];
    const float* b1  = (const float*)d_in[4];
    const float* W2  = (const float*)d_in[5];
    const float* b2  = (const float*)d_in[6];
    const float* Wc1 = (const float*)d_in[7];
    const float* bc1 = (const float*)d_in[8];
    const float* Wc2 = (const float*)d_in[9];
    const float* bc2 = (const float*)d_in[10];
    float* out = (float*)d_out;
    char* wsb = (char*)d_ws;

    const int N = in_sizes[0] / 64;
    const int E = in_sizes[1] / 2;
    const int Q = in_sizes[2] / 2;

    // workspace layout (4-byte units)
    int*   cntRow    = (int*)wsb;                       // [0, 65536)
    int*   cntCol    = (int*)wsb + 65536;               // [65536, 131072)
    float* dis       = (float*)wsb + 131072;            // [131072, 196608)
    int*   offs      = (int*)wsb + 196608;              // N+1
    int*   cursor    = (int*)wsb + 262144;
    int*   bsum      = (int*)wsb + 327680;              // 256
    int*   srcSorted = (int*)wsb + 331776;              // E -> ends 1131776
    float* xs        = (float*)wsb + 1179648;           // N*64  -> ends 4379648
    float* agg1      = (float*)wsb + 4379648;           // N*64  -> ends 7579648
    float* h1s       = (float*)wsb + 7579648;           // N*128 -> ends 13979648
    float* agg2      = (float*)wsb + 13979648;          // N*128 -> ends 20379648
    float* h2        = (float*)wsb + 1179648;           // reuse xs+agg1 region (N*128)

    const int* row  = ei;
    const int* col  = ei + E;
    const int* srcA = eli;
    const int* dstA = eli + Q;

    const int scanB = (N + 1023) / 1024;

    k_zero_i<<<(131072 + 255) / 256, 256, 0, stream>>>(cntRow, 131072);
    k_count<<<(E + 255) / 256, 256, 0, stream>>>(row, col, cntRow, cntCol, E);
    k_dis<<<(N + 255) / 256, 256, 0, stream>>>(cntRow, dis, N);
    k_scan1<<<scanB, 256, 0, stream>>>(cntCol, offs, bsum, N);
    k_scan2<<<1, 256, 0, stream>>>(bsum, scanB);
    k_scan3<<<(N + 255) / 256, 256, 0, stream>>>(offs, cursor, bsum, N, E);
    k_fill<<<(E + 255) / 256, 256, 0, stream>>>(row, col, cursor, srcSorted, E);
    k_xs<<<(N * 16 + 255) / 256, 256, 0, stream>>>(x, dis, xs, N);
    // conv1: agg1 = dis * (xs + gathered xs), d=64
    k_gather<4><<<((size_t)N * 16 + 255) / 256, 256, 0, stream>>>(xs, offs, srcSorted, dis, agg1, N);
    // h1s = relu(agg1 @ W1 + b1) * dis
    k_gemm<64, true, true><<<(N + 31) / 32, 256, 0, stream>>>(agg1, W1, b1, dis, h1s, N);
    // conv2: agg2 = dis * (h1s + gathered h1s), d=128
    k_gather<5><<<((size_t)N * 32 + 255) / 256, 256, 0, stream>>>(h1s, offs, srcSorted, dis, agg2, N);
    // h2 = agg2 @ W2 + b2
    k_gemm<128, false, false><<<(N + 31) / 32, 256, 0, stream>>>(agg2, W2, b2, nullptr, h2, N);
    k_query<<<(Q + 31) / 32, 256, 0, stream>>>(h2, srcA, dstA, Wc1, bc1, Wc2, bc2, out, Q);
}

// Round 3
// 452.560 us; speedup vs baseline: 5.3021x; 1.2108x over previous
//
#include <hip/hip_runtime.h>
#include <hip/hip_bf16.h>

// N=50000, E=800000, Q=200000, d_in=64, h=128
// Pipeline: CSR-by-dest gather convs; head folded to per-node U/V GEMMs + gather-dot.

__global__ __launch_bounds__(256) void k_zero_i(int* __restrict__ p, int n) {
    int i = blockIdx.x * 256 + threadIdx.x;
    if (i < n) p[i] = 0;
}

__global__ __launch_bounds__(256) void k_count(const int* __restrict__ row,
                                               const int* __restrict__ col,
                                               int* __restrict__ cntRow,
                                               int* __restrict__ cntCol, int E) {
    int i = blockIdx.x * 256 + threadIdx.x;
    if (i < E) {
        atomicAdd(&cntRow[row[i]], 1);
        atomicAdd(&cntCol[col[i]], 1);
    }
}

__global__ __launch_bounds__(256) void k_dis(const int* __restrict__ cntRow,
                                             float* __restrict__ dis, int N) {
    int i = blockIdx.x * 256 + threadIdx.x;
    if (i < N) dis[i] = 1.0f / sqrtf((float)(cntRow[i] + 1));
}

__global__ __launch_bounds__(256) void k_scan1(const int* __restrict__ cnt,
                                               int* __restrict__ offs,
                                               int* __restrict__ bsum, int N) {
    __shared__ int ts[256];
    int t = threadIdx.x;
    int base = blockIdx.x * 1024 + t * 4;
    int v0 = (base + 0 < N) ? cnt[base + 0] : 0;
    int v1 = (base + 1 < N) ? cnt[base + 1] : 0;
    int v2 = (base + 2 < N) ? cnt[base + 2] : 0;
    int v3 = (base + 3 < N) ? cnt[base + 3] : 0;
    int sum = v0 + v1 + v2 + v3;
    ts[t] = sum;
    __syncthreads();
    for (int off = 1; off < 256; off <<= 1) {
        int x = (t >= off) ? ts[t - off] : 0;
        __syncthreads();
        ts[t] += x;
        __syncthreads();
    }
    int e = ts[t] - sum;
    if (base + 0 < N) offs[base + 0] = e;
    if (base + 1 < N) offs[base + 1] = e + v0;
    if (base + 2 < N) offs[base + 2] = e + v0 + v1;
    if (base + 3 < N) offs[base + 3] = e + v0 + v1 + v2;
    if (t == 255) bsum[blockIdx.x] = ts[255];
}

__global__ __launch_bounds__(256) void k_scan2(int* __restrict__ bsum, int B) {
    __shared__ int ts[256];
    int t = threadIdx.x;
    int v = (t < B) ? bsum[t] : 0;
    ts[t] = v;
    __syncthreads();
    for (int off = 1; off < 256; off <<= 1) {
        int x = (t >= off) ? ts[t - off] : 0;
        __syncthreads();
        ts[t] += x;
        __syncthreads();
    }
    if (t < B) bsum[t] = ts[t] - v;
}

__global__ __launch_bounds__(256) void k_scan3(int* __restrict__ offs,
                                               int* __restrict__ cursor,
                                               const int* __restrict__ bsum,
                                               int N, int E) {
    int i = blockIdx.x * 256 + threadIdx.x;
    if (i < N) {
        int o = offs[i] + bsum[i >> 10];
        offs[i] = o;
        cursor[i] = o;
    }
    if (i == 0) offs[N] = E;
}

__global__ __launch_bounds__(256) void k_fill(const int* __restrict__ row,
                                              const int* __restrict__ col,
                                              int* __restrict__ cursor,
                                              int* __restrict__ srcSorted, int E) {
    int e = blockIdx.x * 256 + threadIdx.x;
    if (e < E) {
        int c = col[e];
        int pos = atomicAdd(&cursor[c], 1);
        srcSorted[pos] = row[e];
    }
}

// agg[n] = dis[n] * (self + sum over in-edges of s[src] (* dis[src] if SRCSCALE))
// SRCSCALE=true: s unscaled (x), self = s[n]*dis[n].  false: s pre-scaled, self = s[n].
template <int LOGCH, bool SRCSCALE>
__global__ __launch_bounds__(256) void k_gather(const float* __restrict__ s,
                                                const int* __restrict__ offs,
                                                const int* __restrict__ srcs,
                                                const float* __restrict__ dis,
                                                float* __restrict__ agg, int N) {
    int tid = blockIdx.x * 256 + threadIdx.x;
    int node = tid >> LOGCH;
    if (node >= N) return;
    int c4 = (tid & ((1 << LOGCH) - 1)) * 4;
    const int D = 4 << LOGCH;
    int e = offs[node], eEnd = offs[node + 1];
    float dn = dis[node];
    float4 acc = *(const float4*)(s + (size_t)node * D + c4);
    if (SRCSCALE) { acc.x *= dn; acc.y *= dn; acc.z *= dn; acc.w *= dn; }
    int srcNext = (e < eEnd) ? srcs[e] : 0;
    float dNext = SRCSCALE ? dis[srcNext] : 0.f;
    while (e < eEnd) {
        int src = srcNext;
        float dsrc = dNext;
        e++;
        srcNext = (e < eEnd) ? srcs[e] : 0;
        if (SRCSCALE) dNext = dis[srcNext];
        float4 v = *(const float4*)(s + (size_t)src * D + c4);
        if (SRCSCALE) { v.x *= dsrc; v.y *= dsrc; v.z *= dsrc; v.w *= dsrc; }
        acc.x += v.x; acc.y += v.y; acc.z += v.z; acc.w += v.w;
    }
    acc.x *= dn; acc.y *= dn; acc.z *= dn; acc.w *= dn;
    *(float4*)(agg + (size_t)node * D + c4) = acc;
}

// out = act(A[N,K] @ W[K,128] + b) * (SCALE ? dis : 1)
// NOTE: A and out may alias (in-place per-row-block GEMM) -> no __restrict__ on them.
template <int K, bool RELU, bool SCALE>
__global__ __launch_bounds__(256) void k_gemm(const float* A,
                                              const float* __restrict__ W,
                                              const float* __restrict__ b,
                                              const float* __restrict__ dis,
                                              float* out, int N) {
    __shared__ float As[32][36];   // pad 36: 16B-aligned rows for ds_read_b128
    __shared__ float Ws[32][128];
    int t = threadIdx.x;
    int rowBase = blockIdx.x * 32;
    int jg = t & 31;
    int rg = t >> 5;
    float acc[4][4] = {};
    for (int kc = 0; kc < K; kc += 32) {
        {
            int r = t >> 3;
            int kk4 = (t & 7) << 2;
            int gr = rowBase + r;
            float4 v = make_float4(0.f, 0.f, 0.f, 0.f);
            if (gr < N) v = *(const float4*)(A + (size_t)gr * K + kc + kk4);
            *(float4*)(&As[r][kk4]) = v;
        }
        {
            const float4* Wg = (const float4*)(W + (size_t)kc * 128);
            float4* Wl = (float4*)(&Ws[0][0]);
            Wl[t] = Wg[t];
            Wl[t + 256] = Wg[t + 256];
            Wl[t + 512] = Wg[t + 512];
            Wl[t + 768] = Wg[t + 768];
        }
        __syncthreads();
#pragma unroll
        for (int k4 = 0; k4 < 32; k4 += 4) {
            float ar[4][4];
#pragma unroll
            for (int i = 0; i < 4; i++) {
                float4 a = *(const float4*)(&As[rg * 4 + i][k4]);
                ar[i][0] = a.x; ar[i][1] = a.y; ar[i][2] = a.z; ar[i][3] = a.w;
            }
#pragma unroll
            for (int kk = 0; kk < 4; kk++) {
                float4 w = *(const float4*)(&Ws[k4 + kk][jg * 4]);
#pragma unroll
                for (int i = 0; i < 4; i++) {
                    acc[i][0] += ar[i][kk] * w.x;
                    acc[i][1] += ar[i][kk] * w.y;
                    acc[i][2] += ar[i][kk] * w.z;
                    acc[i][3] += ar[i][kk] * w.w;
                }
            }
        }
        __syncthreads();
    }
#pragma unroll
    for (int i = 0; i < 4; i++) {
        int r = rowBase + rg * 4 + i;
        if (r >= N) continue;
        float sc = SCALE ? dis[r] : 1.0f;
        int j = jg * 4;
        float4 bv = *(const float4*)(b + j);
        float4 v;
        v.x = acc[i][0] + bv.x; v.y = acc[i][1] + bv.y;
        v.z = acc[i][2] + bv.z; v.w = acc[i][3] + bv.w;
        if (RELU) {
            v.x = fmaxf(v.x, 0.f); v.y = fmaxf(v.y, 0.f);
            v.z = fmaxf(v.z, 0.f); v.w = fmaxf(v.w, 0.f);
        }
        if (SCALE) { v.x *= sc; v.y *= sc; v.z *= sc; v.w *= sc; }
        *(float4*)(out + (size_t)r * 128 + j) = v;
    }
}

// Fold: Wt = W2 @ Wc1[0:128,:], Wv = W2 @ Wc1[128:256,:]
//       buv[0:128] = b2 @ Wc1[0:128,:] + bc1, buv[128:256] = b2 @ Wc1[128:256,:]
__global__ __launch_bounds__(256) void k_foldW(const float* __restrict__ W2,
                                               const float* __restrict__ Wc1,
                                               const float* __restrict__ b2,
                                               const float* __restrict__ bc1,
                                               float* __restrict__ Wt,
                                               float* __restrict__ Wv,
                                               float* __restrict__ buv) {
    __shared__ float w2row[128];
    int t = threadIdx.x;
    int j = t & 127, half = t >> 7;
    const float* wc = Wc1 + (size_t)half * 128 * 128 + j;
    if (blockIdx.x < 128) {
        int k = blockIdx.x;
        if (t < 128) w2row[t] = W2[k * 128 + t];
        __syncthreads();
        float acc = 0.f;
#pragma unroll 8
        for (int m = 0; m < 128; m++) acc += w2row[m] * wc[(size_t)m * 128];
        (half ? Wv : Wt)[k * 128 + j] = acc;
    } else {
        float acc = half ? 0.f : bc1[j];
#pragma unroll 8
        for (int m = 0; m < 128; m++) acc += b2[m] * wc[(size_t)m * 128];
        buv[half * 128 + j] = acc;
    }
}

// out[q] = relu(U[src[q]] + V[dst[q]]) . Wc2 + bc2   (16 lanes per query)
__global__ __launch_bounds__(256) void k_head(const float* __restrict__ U,
                                              const float* __restrict__ V,
                                              const int* __restrict__ srcA,
                                              const int* __restrict__ dstA,
                                              const float* __restrict__ Wc2,
                                              const float* __restrict__ bc2,
                                              float* __restrict__ out, int Q) {
    int t = threadIdx.x;
    int q = blockIdx.x * 16 + (t >> 4);
    if (q >= Q) return;
    int l = t & 15;
    int s = srcA[q], d = dstA[q];
    const float4* u = (const float4*)(U + (size_t)s * 128 + l * 8);
    const float4* v = (const float4*)(V + (size_t)d * 128 + l * 8);
    const float4* w = (const float4*)(Wc2 + l * 8);
    float4 u0 = u[0], u1 = u[1];
    float4 v0 = v[0], v1 = v[1];
    float4 w0 = w[0], w1 = w[1];
    float acc = 0.f, z;
    z = fmaxf(u0.x + v0.x, 0.f); acc += z * w0.x;
    z = fmaxf(u0.y + v0.y, 0.f); acc += z * w0.y;
    z = fmaxf(u0.z + v0.z, 0.f); acc += z * w0.z;
    z = fmaxf(u0.w + v0.w, 0.f); acc += z * w0.w;
    z = fmaxf(u1.x + v1.x, 0.f); acc += z * w1.x;
    z = fmaxf(u1.y + v1.y, 0.f); acc += z * w1.y;
    z = fmaxf(u1.z + v1.z, 0.f); acc += z * w1.z;
    z = fmaxf(u1.w + v1.w, 0.f); acc += z * w1.w;
    acc += __shfl_xor(acc, 1);
    acc += __shfl_xor(acc, 2);
    acc += __shfl_xor(acc, 4);
    acc += __shfl_xor(acc, 8);
    if (l == 0) out[q] = acc + bc2[0];
}

extern "C" void kernel_launch(void* const* d_in, const int* in_sizes, int n_in,
                              void* d_out, int out_size, void* d_ws, size_t ws_size,
                              hipStream_t stream) {
    const float* x   = (const float*)d_in[0];
    const int*   ei  = (const int*)d_in[1];
    const int*   eli = (const int*)d_in[2];
    const float* W1  = (const float*)d_in[3];
    const float* b1  = (const float*)d_in[4];
    const float* W2  = (const float*)d_in[5];
    const float* b2  = (const float*)d_in[6];
    const float* Wc1 = (const float*)d_in[7];
    const float* bc1 = (const float*)d_in[8];
    const float* Wc2 = (const float*)d_in[9];
    const float* bc2 = (const float*)d_in[10];
    float* out = (float*)d_out;
    char* wsb = (char*)d_ws;

    const int N = in_sizes[0] / 64;
    const int E = in_sizes[1] / 2;
    const int Q = in_sizes[2] / 2;

    // workspace layout (4-byte units) — same peak footprint as round 2
    int*   cntRow    = (int*)wsb;               // 65536
    int*   cntCol    = (int*)wsb + 65536;
    float* dis       = (float*)wsb + 131072;
    int*   offs      = (int*)wsb + 196608;      // N+1
    int*   cursor    = (int*)wsb + 262144;
    int*   bsum      = (int*)wsb + 327680;      // 256
    int*   srcSorted = (int*)wsb + 331776;      // E -> ends 1131776
    float* Wt        = (float*)wsb + 1179648;   // 16384
    float* Wv        = (float*)wsb + 1212416;   // 16384
    float* buv       = (float*)wsb + 1245184;   // 256
    float* agg1      = (float*)wsb + 4379648;   // N*64
    float* h1s       = (float*)wsb + 7579648;   // N*128 ; reused as U
    float* agg2      = (float*)wsb + 13979648;  // N*128 ; V written in-place
    float* U         = h1s;
    float* V         = agg2;

    const int* row  = ei;
    const int* col  = ei + E;
    const int* srcA = eli;
    const int* dstA = eli + Q;

    const int scanB = (N + 1023) / 1024;

    k_zero_i<<<(131072 + 255) / 256, 256, 0, stream>>>(cntRow, 131072);
    k_count<<<(E + 255) / 256, 256, 0, stream>>>(row, col, cntRow, cntCol, E);
    k_dis<<<(N + 255) / 256, 256, 0, stream>>>(cntRow, dis, N);
    k_scan1<<<scanB, 256, 0, stream>>>(cntCol, offs, bsum, N);
    k_scan2<<<1, 256, 0, stream>>>(bsum, scanB);
    k_scan3<<<(N + 255) / 256, 256, 0, stream>>>(offs, cursor, bsum, N, E);
    k_fill<<<(E + 255) / 256, 256, 0, stream>>>(row, col, cursor, srcSorted, E);
    k_foldW<<<129, 256, 0, stream>>>(W2, Wc1, b2, bc1, Wt, Wv, buv);
    // conv1: agg1 = dis * (x*dis self + sum x[src]*dis[src]), d=64
    k_gather<4, true><<<((size_t)N * 16 + 255) / 256, 256, 0, stream>>>(x, offs, srcSorted, dis, agg1, N);
    // h1s = relu(agg1 @ W1 + b1) * dis
    k_gemm<64, true, true><<<(N + 31) / 32, 256, 0, stream>>>(agg1, W1, b1, dis, h1s, N);
    // conv2: agg2 = dis * (h1s self + sum h1s[src]), d=128
    k_gather<5, false><<<((size_t)N * 32 + 255) / 256, 256, 0, stream>>>(h1s, offs, srcSorted, dis, agg2, N);
    // U = agg2 @ Wt + (b2@Wc1_top + bc1)   (overwrites h1s, which is dead)
    k_gemm<128, false, false><<<(N + 31) / 32, 256, 0, stream>>>(agg2, Wt, buv, nullptr, U, N);
    // V = agg2 @ Wv + b2@Wc1_bot           (in-place over agg2)
    k_gemm<128, false, false><<<(N + 31) / 32, 256, 0, stream>>>(agg2, Wv, buv + 128, nullptr, V, N);
    // head
    k_head<<<(Q + 15) / 16, 256, 0, stream>>>(U, V, srcA, dstA, Wc2, bc2, out, Q);
}

// Round 4
// 408.907 us; speedup vs baseline: 5.8682x; 1.1068x over previous
//
#include <hip/hip_runtime.h>
#include <hip/hip_bf16.h>

// N=50000, E=800000, Q=200000, d_in=64, h=128
// CSR-by-dest gather convs; head folded to per-node U/V GEMMs + gather-dot.
// Degree counting via LDS-privatized partial histograms (no global atomics).

#define HB 256  // histogram blocks

// Per-block 16-bit-packed partial histograms of row[] and col[].
// Two bin-range passes (16384 words = 64KB LDS) -> overflow-safe for any input.
__global__ __launch_bounds__(256) void k_hist(const int* __restrict__ row,
                                              const int* __restrict__ col,
                                              unsigned int* __restrict__ hRow,
                                              unsigned int* __restrict__ hCol,
                                              int E, int W, int chunk) {
    __shared__ unsigned int lds[16384];
    int t = threadIdx.x, b = blockIdx.x;
    int e0 = b * chunk, e1 = min(E, e0 + chunk);
    for (int p = 0; p < 2; p++) {
        const int* idxArr = p ? col : row;
        unsigned int* outArr = p ? hCol : hRow;
        for (int base = 0; base < W; base += 16384) {
            int wcap = min(W - base, 16384);
            for (int i = t; i < wcap; i += 256) lds[i] = 0;
            __syncthreads();
            for (int e = e0 + t; e < e1; e += 256) {
                int idx = idxArr[e];
                int w = (idx >> 1) - base;
                if ((unsigned)w < (unsigned)wcap)
                    atomicAdd(&lds[w], 1u << ((idx & 1) * 16));
            }
            __syncthreads();
            for (int i = t; i < wcap; i += 256)
                outArr[(size_t)b * W + base + i] = lds[i];
            __syncthreads();
        }
    }
}

// Sum 16-bit lanes across HB partials; emit cntCol (int) and dis = (deg_row+1)^-0.5
__global__ __launch_bounds__(256) void k_reduce(const unsigned int* __restrict__ hRow,
                                                const unsigned int* __restrict__ hCol,
                                                int* __restrict__ cntCol,
                                                float* __restrict__ dis,
                                                int N, int W) {
    int w = blockIdx.x * 256 + threadIdx.x;
    if (w >= W) return;
    unsigned int r0 = 0, r1 = 0, c0 = 0, c1 = 0;
#pragma unroll 8
    for (int b = 0; b < HB; b++) {
        unsigned int hr = hRow[(size_t)b * W + w];
        unsigned int hc = hCol[(size_t)b * W + w];
        r0 += hr & 0xFFFFu; r1 += hr >> 16;
        c0 += hc & 0xFFFFu; c1 += hc >> 16;
    }
    int n0 = 2 * w, n1 = 2 * w + 1;
    cntCol[n0] = (int)c0;
    dis[n0] = 1.0f / sqrtf((float)(r0 + 1));
    if (n1 < N) {
        cntCol[n1] = (int)c1;
        dis[n1] = 1.0f / sqrtf((float)(r1 + 1));
    }
}

__global__ __launch_bounds__(256) void k_scan1(const int* __restrict__ cnt,
                                               int* __restrict__ offs,
                                               int* __restrict__ bsum, int N) {
    __shared__ int ts[256];
    int t = threadIdx.x;
    int base = blockIdx.x * 1024 + t * 4;
    int v0 = (base + 0 < N) ? cnt[base + 0] : 0;
    int v1 = (base + 1 < N) ? cnt[base + 1] : 0;
    int v2 = (base + 2 < N) ? cnt[base + 2] : 0;
    int v3 = (base + 3 < N) ? cnt[base + 3] : 0;
    int sum = v0 + v1 + v2 + v3;
    ts[t] = sum;
    __syncthreads();
    for (int off = 1; off < 256; off <<= 1) {
        int x = (t >= off) ? ts[t - off] : 0;
        __syncthreads();
        ts[t] += x;
        __syncthreads();
    }
    int e = ts[t] - sum;
    if (base + 0 < N) offs[base + 0] = e;
    if (base + 1 < N) offs[base + 1] = e + v0;
    if (base + 2 < N) offs[base + 2] = e + v0 + v1;
    if (base + 3 < N) offs[base + 3] = e + v0 + v1 + v2;
    if (t == 255) bsum[blockIdx.x] = ts[255];
}

__global__ __launch_bounds__(256) void k_scan2(int* __restrict__ bsum, int B) {
    __shared__ int ts[256];
    int t = threadIdx.x;
    int v = (t < B) ? bsum[t] : 0;
    ts[t] = v;
    __syncthreads();
    for (int off = 1; off < 256; off <<= 1) {
        int x = (t >= off) ? ts[t - off] : 0;
        __syncthreads();
        ts[t] += x;
        __syncthreads();
    }
    if (t < B) bsum[t] = ts[t] - v;
}

__global__ __launch_bounds__(256) void k_scan3(int* __restrict__ offs,
                                               int* __restrict__ cursor,
                                               const int* __restrict__ bsum,
                                               int N, int E) {
    int i = blockIdx.x * 256 + threadIdx.x;
    if (i < N) {
        int o = offs[i] + bsum[i >> 10];
        offs[i] = o;
        cursor[i] = o;
    }
    if (i == 0) offs[N] = E;
}

__global__ __launch_bounds__(256) void k_fill(const int* __restrict__ row,
                                              const int* __restrict__ col,
                                              int* __restrict__ cursor,
                                              int* __restrict__ srcSorted, int E) {
    int e = blockIdx.x * 256 + threadIdx.x;
    if (e < E) {
        int c = col[e];
        int pos = atomicAdd(&cursor[c], 1);
        srcSorted[pos] = row[e];
    }
}

// agg[n] = dis[n] * (self + sum over in-edges of s[src] (* dis[src] if SRCSCALE))
template <int LOGCH, bool SRCSCALE>
__global__ __launch_bounds__(256) void k_gather(const float* __restrict__ s,
                                                const int* __restrict__ offs,
                                                const int* __restrict__ srcs,
                                                const float* __restrict__ dis,
                                                float* __restrict__ agg, int N) {
    int tid = blockIdx.x * 256 + threadIdx.x;
    int node = tid >> LOGCH;
    if (node >= N) return;
    int c4 = (tid & ((1 << LOGCH) - 1)) * 4;
    const int D = 4 << LOGCH;
    int e = offs[node], eEnd = offs[node + 1];
    float dn = dis[node];
    float4 acc = *(const float4*)(s + (size_t)node * D + c4);
    if (SRCSCALE) { acc.x *= dn; acc.y *= dn; acc.z *= dn; acc.w *= dn; }
    int srcNext = (e < eEnd) ? srcs[e] : 0;
    float dNext = SRCSCALE ? dis[srcNext] : 0.f;
    while (e < eEnd) {
        int src = srcNext;
        float dsrc = dNext;
        e++;
        srcNext = (e < eEnd) ? srcs[e] : 0;
        if (SRCSCALE) dNext = dis[srcNext];
        float4 v = *(const float4*)(s + (size_t)src * D + c4);
        if (SRCSCALE) { v.x *= dsrc; v.y *= dsrc; v.z *= dsrc; v.w *= dsrc; }
        acc.x += v.x; acc.y += v.y; acc.z += v.z; acc.w += v.w;
    }
    acc.x *= dn; acc.y *= dn; acc.z *= dn; acc.w *= dn;
    *(float4*)(agg + (size_t)node * D + c4) = acc;
}

// out = act(A[N,K] @ W[K,128] + b) * (SCALE ? dis : 1)
template <int K, bool RELU, bool SCALE>
__global__ __launch_bounds__(256) void k_gemm(const float* A,
                                              const float* __restrict__ W,
                                              const float* __restrict__ b,
                                              const float* __restrict__ dis,
                                              float* out, int N) {
    __shared__ float As[32][36];
    __shared__ float Ws[32][128];
    int t = threadIdx.x;
    int rowBase = blockIdx.x * 32;
    int jg = t & 31;
    int rg = t >> 5;
    float acc[4][4] = {};
    for (int kc = 0; kc < K; kc += 32) {
        {
            int r = t >> 3;
            int kk4 = (t & 7) << 2;
            int gr = rowBase + r;
            float4 v = make_float4(0.f, 0.f, 0.f, 0.f);
            if (gr < N) v = *(const float4*)(A + (size_t)gr * K + kc + kk4);
            *(float4*)(&As[r][kk4]) = v;
        }
        {
            const float4* Wg = (const float4*)(W + (size_t)kc * 128);
            float4* Wl = (float4*)(&Ws[0][0]);
            Wl[t] = Wg[t];
            Wl[t + 256] = Wg[t + 256];
            Wl[t + 512] = Wg[t + 512];
            Wl[t + 768] = Wg[t + 768];
        }
        __syncthreads();
#pragma unroll
        for (int k4 = 0; k4 < 32; k4 += 4) {
            float ar[4][4];
#pragma unroll
            for (int i = 0; i < 4; i++) {
                float4 a = *(const float4*)(&As[rg * 4 + i][k4]);
                ar[i][0] = a.x; ar[i][1] = a.y; ar[i][2] = a.z; ar[i][3] = a.w;
            }
#pragma unroll
            for (int kk = 0; kk < 4; kk++) {
                float4 w = *(const float4*)(&Ws[k4 + kk][jg * 4]);
#pragma unroll
                for (int i = 0; i < 4; i++) {
                    acc[i][0] += ar[i][kk] * w.x;
                    acc[i][1] += ar[i][kk] * w.y;
                    acc[i][2] += ar[i][kk] * w.z;
                    acc[i][3] += ar[i][kk] * w.w;
                }
            }
        }
        __syncthreads();
    }
#pragma unroll
    for (int i = 0; i < 4; i++) {
        int r = rowBase + rg * 4 + i;
        if (r >= N) continue;
        float sc = SCALE ? dis[r] : 1.0f;
        int j = jg * 4;
        float4 bv = *(const float4*)(b + j);
        float4 v;
        v.x = acc[i][0] + bv.x; v.y = acc[i][1] + bv.y;
        v.z = acc[i][2] + bv.z; v.w = acc[i][3] + bv.w;
        if (RELU) {
            v.x = fmaxf(v.x, 0.f); v.y = fmaxf(v.y, 0.f);
            v.z = fmaxf(v.z, 0.f); v.w = fmaxf(v.w, 0.f);
        }
        if (SCALE) { v.x *= sc; v.y *= sc; v.z *= sc; v.w *= sc; }
        *(float4*)(out + (size_t)r * 128 + j) = v;
    }
}

// U = A@Wt + buv[0:128], V = A@Wv + buv[128:256]; V may alias A (in-place).
__global__ __launch_bounds__(256) void k_gemmUV(const float* A,
                                                const float* __restrict__ Wt,
                                                const float* __restrict__ Wv,
                                                const float* __restrict__ buv,
                                                float* U, float* V, int N) {
    __shared__ float As[32][36];
    __shared__ float Wts[32][128];
    __shared__ float Wvs[32][128];
    int t = threadIdx.x;
    int rowBase = blockIdx.x * 32;
    int jg = t & 31;
    int rg = t >> 5;
    float accU[4][4] = {}, accV[4][4] = {};
    for (int kc = 0; kc < 128; kc += 32) {
        {
            int r = t >> 3;
            int kk4 = (t & 7) << 2;
            int gr = rowBase + r;
            float4 v = make_float4(0.f, 0.f, 0.f, 0.f);
            if (gr < N) v = *(const float4*)(A + (size_t)gr * 128 + kc + kk4);
            *(float4*)(&As[r][kk4]) = v;
        }
        {
            const float4* Wg = (const float4*)(Wt + (size_t)kc * 128);
            const float4* Vg = (const float4*)(Wv + (size_t)kc * 128);
            float4* Wl = (float4*)(&Wts[0][0]);
            float4* Vl = (float4*)(&Wvs[0][0]);
#pragma unroll
            for (int s = 0; s < 4; s++) {
                Wl[t + s * 256] = Wg[t + s * 256];
                Vl[t + s * 256] = Vg[t + s * 256];
            }
        }
        __syncthreads();
#pragma unroll
        for (int k4 = 0; k4 < 32; k4 += 4) {
            float ar[4][4];
#pragma unroll
            for (int i = 0; i < 4; i++) {
                float4 a = *(const float4*)(&As[rg * 4 + i][k4]);
                ar[i][0] = a.x; ar[i][1] = a.y; ar[i][2] = a.z; ar[i][3] = a.w;
            }
#pragma unroll
            for (int kk = 0; kk < 4; kk++) {
                float4 wt = *(const float4*)(&Wts[k4 + kk][jg * 4]);
                float4 wv = *(const float4*)(&Wvs[k4 + kk][jg * 4]);
#pragma unroll
                for (int i = 0; i < 4; i++) {
                    accU[i][0] += ar[i][kk] * wt.x;
                    accU[i][1] += ar[i][kk] * wt.y;
                    accU[i][2] += ar[i][kk] * wt.z;
                    accU[i][3] += ar[i][kk] * wt.w;
                    accV[i][0] += ar[i][kk] * wv.x;
                    accV[i][1] += ar[i][kk] * wv.y;
                    accV[i][2] += ar[i][kk] * wv.z;
                    accV[i][3] += ar[i][kk] * wv.w;
                }
            }
        }
        __syncthreads();
    }
    int j = jg * 4;
    float4 bu = *(const float4*)(buv + j);
    float4 bv2 = *(const float4*)(buv + 128 + j);
#pragma unroll
    for (int i = 0; i < 4; i++) {
        int r = rowBase + rg * 4 + i;
        if (r >= N) continue;
        float4 u, v;
        u.x = accU[i][0] + bu.x; u.y = accU[i][1] + bu.y;
        u.z = accU[i][2] + bu.z; u.w = accU[i][3] + bu.w;
        v.x = accV[i][0] + bv2.x; v.y = accV[i][1] + bv2.y;
        v.z = accV[i][2] + bv2.z; v.w = accV[i][3] + bv2.w;
        *(float4*)(U + (size_t)r * 128 + j) = u;
        *(float4*)(V + (size_t)r * 128 + j) = v;
    }
}

// Fold: Wt = W2 @ Wc1[0:128,:], Wv = W2 @ Wc1[128:256,:]
//       buv[0:128] = b2 @ Wc1_top + bc1, buv[128:256] = b2 @ Wc1_bot
__global__ __launch_bounds__(256) void k_foldW(const float* __restrict__ W2,
                                               const float* __restrict__ Wc1,
                                               const float* __restrict__ b2,
                                               const float* __restrict__ bc1,
                                               float* __restrict__ Wt,
                                               float* __restrict__ Wv,
                                               float* __restrict__ buv) {
    __shared__ float w2row[128];
    int t = threadIdx.x;
    int j = t & 127, half = t >> 7;
    const float* wc = Wc1 + (size_t)half * 128 * 128 + j;
    if (blockIdx.x < 128) {
        int k = blockIdx.x;
        if (t < 128) w2row[t] = W2[k * 128 + t];
        __syncthreads();
        float acc = 0.f;
#pragma unroll 8
        for (int m = 0; m < 128; m++) acc += w2row[m] * wc[(size_t)m * 128];
        (half ? Wv : Wt)[k * 128 + j] = acc;
    } else {
        float acc = half ? 0.f : bc1[j];
#pragma unroll 8
        for (int m = 0; m < 128; m++) acc += b2[m] * wc[(size_t)m * 128];
        buv[half * 128 + j] = acc;
    }
}

// out[q] = relu(U[src[q]] + V[dst[q]]) . Wc2 + bc2
__global__ __launch_bounds__(256) void k_head(const float* __restrict__ U,
                                              const float* __restrict__ V,
                                              const int* __restrict__ srcA,
                                              const int* __restrict__ dstA,
                                              const float* __restrict__ Wc2,
                                              const float* __restrict__ bc2,
                                              float* __restrict__ out, int Q) {
    int t = threadIdx.x;
    int q = blockIdx.x * 16 + (t >> 4);
    if (q >= Q) return;
    int l = t & 15;
    int s = srcA[q], d = dstA[q];
    const float4* u = (const float4*)(U + (size_t)s * 128 + l * 8);
    const float4* v = (const float4*)(V + (size_t)d * 128 + l * 8);
    const float4* w = (const float4*)(Wc2 + l * 8);
    float4 u0 = u[0], u1 = u[1];
    float4 v0 = v[0], v1 = v[1];
    float4 w0 = w[0], w1 = w[1];
    float acc = 0.f, z;
    z = fmaxf(u0.x + v0.x, 0.f); acc += z * w0.x;
    z = fmaxf(u0.y + v0.y, 0.f); acc += z * w0.y;
    z = fmaxf(u0.z + v0.z, 0.f); acc += z * w0.z;
    z = fmaxf(u0.w + v0.w, 0.f); acc += z * w0.w;
    z = fmaxf(u1.x + v1.x, 0.f); acc += z * w1.x;
    z = fmaxf(u1.y + v1.y, 0.f); acc += z * w1.y;
    z = fmaxf(u1.z + v1.z, 0.f); acc += z * w1.z;
    z = fmaxf(u1.w + v1.w, 0.f); acc += z * w1.w;
    acc += __shfl_xor(acc, 1);
    acc += __shfl_xor(acc, 2);
    acc += __shfl_xor(acc, 4);
    acc += __shfl_xor(acc, 8);
    if (l == 0) out[q] = acc + bc2[0];
}

extern "C" void kernel_launch(void* const* d_in, const int* in_sizes, int n_in,
                              void* d_out, int out_size, void* d_ws, size_t ws_size,
                              hipStream_t stream) {
    const float* x   = (const float*)d_in[0];
    const int*   ei  = (const int*)d_in[1];
    const int*   eli = (const int*)d_in[2];
    const float* W1  = (const float*)d_in[3];
    const float* b1  = (const float*)d_in[4];
    const float* W2  = (const float*)d_in[5];
    const float* b2  = (const float*)d_in[6];
    const float* Wc1 = (const float*)d_in[7];
    const float* bc1 = (const float*)d_in[8];
    const float* Wc2 = (const float*)d_in[9];
    const float* bc2 = (const float*)d_in[10];
    float* out = (float*)d_out;
    char* wsb = (char*)d_ws;

    const int N = in_sizes[0] / 64;
    const int E = in_sizes[1] / 2;
    const int Q = in_sizes[2] / 2;
    const int W = (N + 1) / 2;             // packed histogram words
    const int chunk = (E + HB - 1) / HB;

    // workspace layout (4-byte units); peak 20379648 floats = 81.5 MB
    float* dis       = (float*)wsb;             // 65536
    int*   offs      = (int*)wsb + 65536;       // N+1
    int*   cursor    = (int*)wsb + 131072;
    int*   bsum      = (int*)wsb + 196608;      // 256
    int*   cntCol    = (int*)wsb + 262144;      // 65536
    int*   srcSorted = (int*)wsb + 327680;      // E -> ends 1127680
    float* Wt        = (float*)wsb + 1179648;   // 16384
    float* Wv        = (float*)wsb + 1196032;   // 16384
    float* buv       = (float*)wsb + 1212416;   // 256
    float* agg1      = (float*)wsb + 4379648;   // N*64  -> ends 7579648
    float* h1s       = (float*)wsb + 7579648;   // N*128 -> ends 13979648 ; reused as U
    float* agg2      = (float*)wsb + 13979648;  // N*128 -> ends 20379648 ; V in-place
    // hist partials overlap agg regions (dead before gather writes them)
    unsigned int* hRow = (unsigned int*)wsb + 4379648;   // HB*W -> ends 10779648
    unsigned int* hCol = (unsigned int*)wsb + 10779648;  // HB*W -> ends 17179648
    float* U = h1s;
    float* V = agg2;

    const int* row  = ei;
    const int* col  = ei + E;
    const int* srcA = eli;
    const int* dstA = eli + Q;

    const int scanB = (N + 1023) / 1024;

    k_hist<<<HB, 256, 0, stream>>>(row, col, hRow, hCol, E, W, chunk);
    k_reduce<<<(W + 255) / 256, 256, 0, stream>>>(hRow, hCol, cntCol, dis, N, W);
    k_scan1<<<scanB, 256, 0, stream>>>(cntCol, offs, bsum, N);
    k_scan2<<<1, 256, 0, stream>>>(bsum, scanB);
    k_scan3<<<(N + 255) / 256, 256, 0, stream>>>(offs, cursor, bsum, N, E);
    k_fill<<<(E + 255) / 256, 256, 0, stream>>>(row, col, cursor, srcSorted, E);
    k_foldW<<<129, 256, 0, stream>>>(W2, Wc1, b2, bc1, Wt, Wv, buv);
    k_gather<4, true><<<((size_t)N * 16 + 255) / 256, 256, 0, stream>>>(x, offs, srcSorted, dis, agg1, N);
    k_gemm<64, true, true><<<(N + 31) / 32, 256, 0, stream>>>(agg1, W1, b1, dis, h1s, N);
    k_gather<5, false><<<((size_t)N * 32 + 255) / 256, 256, 0, stream>>>(h1s, offs, srcSorted, dis, agg2, N);
    k_gemmUV<<<(N + 31) / 32, 256, 0, stream>>>(agg2, Wt, Wv, buv, U, V, N);
    k_head<<<(Q + 15) / 16, 256, 0, stream>>>(U, V, srcA, dstA, Wc2, bc2, out, Q);
}

// Round 5
// 363.831 us; speedup vs baseline: 6.5952x; 1.1239x over previous
//
#include <hip/hip_runtime.h>

// N=50000, E=800000, Q=200000, d_in=64, h=128
// CSR-by-dest gather convs (emitting split-bf16), MFMA split-bf16 GEMMs,
// folded U/V head + gather-dot. No feature atomics anywhere.

#define HB 128  // histogram blocks

typedef __attribute__((ext_vector_type(8))) short short8;
typedef __attribute__((ext_vector_type(4))) float floatx4;

static __device__ __forceinline__ unsigned int f2bf(float v) {
    union { float f; unsigned int u; } c; c.f = v;
    unsigned int lsb = (c.u >> 16) & 1u;
    c.u += 0x7FFFu + lsb;                 // round-to-nearest-even
    return c.u >> 16;
}
static __device__ __forceinline__ float bf2f(unsigned int h) {
    union { float f; unsigned int u; } c; c.u = h << 16;
    return c.f;
}
// write 4 floats as split bf16 (hi then residual-lo), 8B each
static __device__ __forceinline__ void store_split4(float4 v,
                                                    unsigned short* hi,
                                                    unsigned short* lo) {
    unsigned int h0 = f2bf(v.x), h1 = f2bf(v.y), h2 = f2bf(v.z), h3 = f2bf(v.w);
    uint2 hw; hw.x = h0 | (h1 << 16); hw.y = h2 | (h3 << 16);
    unsigned int l0 = f2bf(v.x - bf2f(h0)), l1 = f2bf(v.y - bf2f(h1));
    unsigned int l2 = f2bf(v.z - bf2f(h2)), l3 = f2bf(v.w - bf2f(h3));
    uint2 lw; lw.x = l0 | (l1 << 16); lw.y = l2 | (l3 << 16);
    *(uint2*)hi = hw;
    *(uint2*)lo = lw;
}

// ---------- degree histogram (LDS-privatized, 16-bit packed) ----------
__global__ __launch_bounds__(256) void k_hist(const int* __restrict__ row,
                                              const int* __restrict__ col,
                                              unsigned int* __restrict__ hRow,
                                              unsigned int* __restrict__ hCol,
                                              int E, int W, int chunk) {
    __shared__ unsigned int lds[16384];
    int t = threadIdx.x, b = blockIdx.x;
    int e0 = b * chunk, e1 = min(E, e0 + chunk);
    for (int p = 0; p < 2; p++) {
        const int* idxArr = p ? col : row;
        unsigned int* outArr = p ? hCol : hRow;
        for (int base = 0; base < W; base += 16384) {
            int wcap = min(W - base, 16384);
            for (int i = t; i < wcap; i += 256) lds[i] = 0;
            __syncthreads();
            for (int e = e0 + t; e < e1; e += 256) {
                int idx = idxArr[e];
                int w = (idx >> 1) - base;
                if ((unsigned)w < (unsigned)wcap)
                    atomicAdd(&lds[w], 1u << ((idx & 1) * 16));
            }
            __syncthreads();
            for (int i = t; i < wcap; i += 256)
                outArr[(size_t)b * W + base + i] = lds[i];
            __syncthreads();
        }
    }
}

__global__ __launch_bounds__(256) void k_reduce(const unsigned int* __restrict__ hRow,
                                                const unsigned int* __restrict__ hCol,
                                                int* __restrict__ cntCol,
                                                float* __restrict__ dis,
                                                int N, int W) {
    int w = blockIdx.x * 256 + threadIdx.x;
    if (w >= W) return;
    unsigned int r0 = 0, r1 = 0, c0 = 0, c1 = 0;
#pragma unroll 8
    for (int b = 0; b < HB; b++) {
        unsigned int hr = hRow[(size_t)b * W + w];
        unsigned int hc = hCol[(size_t)b * W + w];
        r0 += hr & 0xFFFFu; r1 += hr >> 16;
        c0 += hc & 0xFFFFu; c1 += hc >> 16;
    }
    int n0 = 2 * w, n1 = 2 * w + 1;
    cntCol[n0] = (int)c0;
    dis[n0] = 1.0f / sqrtf((float)(r0 + 1));
    if (n1 < N) {
        cntCol[n1] = (int)c1;
        dis[n1] = 1.0f / sqrtf((float)(r1 + 1));
    }
}

// ---------- scan ----------
__global__ __launch_bounds__(256) void k_scan1(const int* __restrict__ cnt,
                                               int* __restrict__ offs,
                                               int* __restrict__ bsum, int N) {
    __shared__ int ts[256];
    int t = threadIdx.x;
    int base = blockIdx.x * 1024 + t * 4;
    int v0 = (base + 0 < N) ? cnt[base + 0] : 0;
    int v1 = (base + 1 < N) ? cnt[base + 1] : 0;
    int v2 = (base + 2 < N) ? cnt[base + 2] : 0;
    int v3 = (base + 3 < N) ? cnt[base + 3] : 0;
    int sum = v0 + v1 + v2 + v3;
    ts[t] = sum;
    __syncthreads();
    for (int off = 1; off < 256; off <<= 1) {
        int x = (t >= off) ? ts[t - off] : 0;
        __syncthreads();
        ts[t] += x;
        __syncthreads();
    }
    int e = ts[t] - sum;
    if (base + 0 < N) offs[base + 0] = e;
    if (base + 1 < N) offs[base + 1] = e + v0;
    if (base + 2 < N) offs[base + 2] = e + v0 + v1;
    if (base + 3 < N) offs[base + 3] = e + v0 + v1 + v2;
    if (t == 255) bsum[blockIdx.x] = ts[255];
}

__global__ __launch_bounds__(256) void k_scan2(int* __restrict__ bsum, int B) {
    __shared__ int ts[256];
    int t = threadIdx.x;
    int v = (t < B) ? bsum[t] : 0;
    ts[t] = v;
    __syncthreads();
    for (int off = 1; off < 256; off <<= 1) {
        int x = (t >= off) ? ts[t - off] : 0;
        __syncthreads();
        ts[t] += x;
        __syncthreads();
    }
    if (t < B) bsum[t] = ts[t] - v;
}

__global__ __launch_bounds__(256) void k_scan3(int* __restrict__ offs,
                                               int* __restrict__ cursor,
                                               const int* __restrict__ bsum,
                                               int N, int E) {
    int i = blockIdx.x * 256 + threadIdx.x;
    if (i < N) {
        int o = offs[i] + bsum[i >> 10];
        offs[i] = o;
        cursor[i] = o;
    }
    if (i == 0) offs[N] = E;
}

__global__ __launch_bounds__(256) void k_fill(const int* __restrict__ row,
                                              const int* __restrict__ col,
                                              int* __restrict__ cursor,
                                              int* __restrict__ srcSorted, int E) {
    int e = blockIdx.x * 256 + threadIdx.x;
    if (e < E) {
        int c = col[e];
        int pos = atomicAdd(&cursor[c], 1);
        srcSorted[pos] = row[e];
    }
}

// ---------- gather conv (fp32 in, split-bf16 out) ----------
template <int LOGCH, bool SRCSCALE>
__global__ __launch_bounds__(256) void k_gather(const float* __restrict__ s,
                                                const int* __restrict__ offs,
                                                const int* __restrict__ srcs,
                                                const float* __restrict__ dis,
                                                unsigned short* __restrict__ aggHi,
                                                unsigned short* __restrict__ aggLo,
                                                int N) {
    int tid = blockIdx.x * 256 + threadIdx.x;
    int node = tid >> LOGCH;
    if (node >= N) return;
    int c4 = (tid & ((1 << LOGCH) - 1)) * 4;
    const int D = 4 << LOGCH;
    int e = offs[node], eEnd = offs[node + 1];
    float dn = dis[node];
    float4 acc = *(const float4*)(s + (size_t)node * D + c4);
    if (SRCSCALE) { acc.x *= dn; acc.y *= dn; acc.z *= dn; acc.w *= dn; }
    int srcNext = (e < eEnd) ? srcs[e] : 0;
    float dNext = SRCSCALE ? dis[srcNext] : 0.f;
    while (e < eEnd) {
        int src = srcNext;
        float dsrc = dNext;
        e++;
        srcNext = (e < eEnd) ? srcs[e] : 0;
        if (SRCSCALE) dNext = dis[srcNext];
        float4 v = *(const float4*)(s + (size_t)src * D + c4);
        if (SRCSCALE) { v.x *= dsrc; v.y *= dsrc; v.z *= dsrc; v.w *= dsrc; }
        acc.x += v.x; acc.y += v.y; acc.z += v.z; acc.w += v.w;
    }
    acc.x *= dn; acc.y *= dn; acc.z *= dn; acc.w *= dn;
    store_split4(acc, aggHi + (size_t)node * D + c4, aggLo + (size_t)node * D + c4);
}

// ---------- fold + pack weights ----------
// blocks 0..127: Wfull[k][n] = (W2 @ [Wc1_top | Wc1_bot])[k][n], packed to MFMA B-frag (split bf16)
// block 128:     buv = [b2@Wc1_top + bc1 | b2@Wc1_bot]
// blocks 129..160: pack W1 (64x128) to MFMA B-frag (split bf16)
__global__ __launch_bounds__(256) void k_fold(const float* __restrict__ W1,
                                              const float* __restrict__ W2,
                                              const float* __restrict__ Wc1,
                                              const float* __restrict__ b2,
                                              const float* __restrict__ bc1,
                                              unsigned short* __restrict__ UVhi,
                                              unsigned short* __restrict__ UVlo,
                                              unsigned short* __restrict__ W1hi,
                                              unsigned short* __restrict__ W1lo,
                                              float* __restrict__ buv) {
    __shared__ float w2row[128];
    int t = threadIdx.x, b = blockIdx.x;
    if (b < 128) {
        int k = b;
        int j = t & 127, half = t >> 7;
        int n = half * 128 + j;
        const float* wc = Wc1 + (size_t)half * 128 * 128 + j;
        if (t < 128) w2row[t] = W2[k * 128 + t];
        __syncthreads();
        float acc = 0.f;
#pragma unroll 8
        for (int m = 0; m < 128; m++) acc += w2row[m] * wc[(size_t)m * 128];
        int kstep = k >> 5, kl = k & 31, quad = kl >> 3, j8 = kl & 7;
        int nb = n >> 4, l = quad * 16 + (n & 15);
        int pidx = ((kstep * 16 + nb) * 64 + l) * 8 + j8;
        unsigned int h = f2bf(acc);
        UVhi[pidx] = (unsigned short)h;
        UVlo[pidx] = (unsigned short)f2bf(acc - bf2f(h));
    } else if (b == 128) {
        int j = t & 127, half = t >> 7;
        const float* wc = Wc1 + (size_t)half * 128 * 128 + j;
        float acc = half ? 0.f : bc1[j];
#pragma unroll 8
        for (int m = 0; m < 128; m++) acc += b2[m] * wc[(size_t)m * 128];
        buv[half * 128 + j] = acc;
    } else {
        int idx = (b - 129) * 256 + t;  // < 8192
        int k = idx >> 7, n = idx & 127;
        float v = W1[k * 128 + n];
        int kstep = k >> 5, kl = k & 31, quad = kl >> 3, j8 = kl & 7;
        int nb = n >> 4, l = quad * 16 + (n & 15);
        int pidx = ((kstep * 8 + nb) * 64 + l) * 8 + j8;
        unsigned int h = f2bf(v);
        W1hi[pidx] = (unsigned short)h;
        W1lo[pidx] = (unsigned short)f2bf(v - bf2f(h));
    }
}

// ---------- MFMA GEMM 1: h1s = relu(agg1 @ W1 + b1) * dis   [K=64, Ncols=128] ----------
__global__ __launch_bounds__(256) void k_mfma1(const unsigned short* __restrict__ Ahi,
                                               const unsigned short* __restrict__ Alo,
                                               const unsigned short* __restrict__ Bhi,
                                               const unsigned short* __restrict__ Blo,
                                               const float* __restrict__ b1,
                                               const float* __restrict__ dis,
                                               float* __restrict__ h1s, int N) {
    int lane = threadIdx.x & 63, wave = threadIdx.x >> 6;
    int mbase = blockIdx.x * 16;
    int ma = mbase + (lane & 15); if (ma >= N) ma = N - 1;
    int quad = lane >> 4;
    floatx4 acc[2] = {};
#pragma unroll
    for (int ks = 0; ks < 2; ks++) {
        short8 ahi = *(const short8*)(Ahi + (size_t)ma * 64 + ks * 32 + quad * 8);
        short8 alo = *(const short8*)(Alo + (size_t)ma * 64 + ks * 32 + quad * 8);
#pragma unroll
        for (int nt = 0; nt < 2; nt++) {
            int nb = wave * 2 + nt;
            short8 bhi = *(const short8*)(Bhi + ((ks * 8 + nb) * 64 + lane) * 8);
            short8 blo = *(const short8*)(Blo + ((ks * 8 + nb) * 64 + lane) * 8);
            acc[nt] = __builtin_amdgcn_mfma_f32_16x16x32_bf16(ahi, bhi, acc[nt], 0, 0, 0);
            acc[nt] = __builtin_amdgcn_mfma_f32_16x16x32_bf16(ahi, blo, acc[nt], 0, 0, 0);
            acc[nt] = __builtin_amdgcn_mfma_f32_16x16x32_bf16(alo, bhi, acc[nt], 0, 0, 0);
        }
    }
    int md = mbase + quad * 4;
#pragma unroll
    for (int nt = 0; nt < 2; nt++) {
        int n0 = (wave * 2 + nt) * 16 + (lane & 15);
        float bias = b1[n0];
#pragma unroll
        for (int r = 0; r < 4; r++) {
            int node = md + r;
            if (node < N)
                h1s[(size_t)node * 128 + n0] = fmaxf(acc[nt][r] + bias, 0.f) * dis[node];
        }
    }
}

// ---------- MFMA GEMM UV: [U|V] = agg2 @ Wfull + buv   [K=128, Ncols=256] ----------
__global__ __launch_bounds__(256) void k_mfmaUV(const unsigned short* __restrict__ Ahi,
                                                const unsigned short* __restrict__ Alo,
                                                const unsigned short* __restrict__ Bhi,
                                                const unsigned short* __restrict__ Blo,
                                                const float* __restrict__ buv,
                                                float* __restrict__ U,
                                                float* __restrict__ V, int N) {
    int lane = threadIdx.x & 63, wave = threadIdx.x >> 6;
    int mbase = blockIdx.x * 16;
    int ma = mbase + (lane & 15); if (ma >= N) ma = N - 1;
    int quad = lane >> 4;
    floatx4 acc[4] = {};
#pragma unroll
    for (int ks = 0; ks < 4; ks++) {
        short8 ahi = *(const short8*)(Ahi + (size_t)ma * 128 + ks * 32 + quad * 8);
        short8 alo = *(const short8*)(Alo + (size_t)ma * 128 + ks * 32 + quad * 8);
#pragma unroll
        for (int nt = 0; nt < 4; nt++) {
            int nb = wave * 4 + nt;
            short8 bhi = *(const short8*)(Bhi + ((ks * 16 + nb) * 64 + lane) * 8);
            short8 blo = *(const short8*)(Blo + ((ks * 16 + nb) * 64 + lane) * 8);
            acc[nt] = __builtin_amdgcn_mfma_f32_16x16x32_bf16(ahi, bhi, acc[nt], 0, 0, 0);
            acc[nt] = __builtin_amdgcn_mfma_f32_16x16x32_bf16(ahi, blo, acc[nt], 0, 0, 0);
            acc[nt] = __builtin_amdgcn_mfma_f32_16x16x32_bf16(alo, bhi, acc[nt], 0, 0, 0);
        }
    }
    int md = mbase + quad * 4;
#pragma unroll
    for (int nt = 0; nt < 4; nt++) {
        int n0 = wave * 64 + nt * 16 + (lane & 15);
        float bias = buv[n0];
        float* dst = (n0 < 128) ? U : V;
        int cc = n0 & 127;
#pragma unroll
        for (int r = 0; r < 4; r++) {
            int node = md + r;
            if (node < N)
                dst[(size_t)node * 128 + cc] = acc[nt][r] + bias;
        }
    }
}

// ---------- head: out[q] = relu(U[src]+V[dst]) . Wc2 + bc2 ----------
__global__ __launch_bounds__(256) void k_head(const float* __restrict__ U,
                                              const float* __restrict__ V,
                                              const int* __restrict__ srcA,
                                              const int* __restrict__ dstA,
                                              const float* __restrict__ Wc2,
                                              const float* __restrict__ bc2,
                                              float* __restrict__ out, int Q) {
    int t = threadIdx.x;
    int q = blockIdx.x * 16 + (t >> 4);
    if (q >= Q) return;
    int l = t & 15;
    int s = srcA[q], d = dstA[q];
    const float4* u = (const float4*)(U + (size_t)s * 128 + l * 8);
    const float4* v = (const float4*)(V + (size_t)d * 128 + l * 8);
    const float4* w = (const float4*)(Wc2 + l * 8);
    float4 u0 = u[0], u1 = u[1];
    float4 v0 = v[0], v1 = v[1];
    float4 w0 = w[0], w1 = w[1];
    float acc = 0.f, z;
    z = fmaxf(u0.x + v0.x, 0.f); acc += z * w0.x;
    z = fmaxf(u0.y + v0.y, 0.f); acc += z * w0.y;
    z = fmaxf(u0.z + v0.z, 0.f); acc += z * w0.z;
    z = fmaxf(u0.w + v0.w, 0.f); acc += z * w0.w;
    z = fmaxf(u1.x + v1.x, 0.f); acc += z * w1.x;
    z = fmaxf(u1.y + v1.y, 0.f); acc += z * w1.y;
    z = fmaxf(u1.z + v1.z, 0.f); acc += z * w1.z;
    z = fmaxf(u1.w + v1.w, 0.f); acc += z * w1.w;
    acc += __shfl_xor(acc, 1);
    acc += __shfl_xor(acc, 2);
    acc += __shfl_xor(acc, 4);
    acc += __shfl_xor(acc, 8);
    if (l == 0) out[q] = acc + bc2[0];
}

extern "C" void kernel_launch(void* const* d_in, const int* in_sizes, int n_in,
                              void* d_out, int out_size, void* d_ws, size_t ws_size,
                              hipStream_t stream) {
    const float* x   = (const float*)d_in[0];
    const int*   ei  = (const int*)d_in[1];
    const int*   eli = (const int*)d_in[2];
    const float* W1  = (const float*)d_in[3];
    const float* b1  = (const float*)d_in[4];
    const float* W2  = (const float*)d_in[5];
    const float* b2  = (const float*)d_in[6];
    const float* Wc1 = (const float*)d_in[7];
    const float* bc1 = (const float*)d_in[8];
    const float* Wc2 = (const float*)d_in[9];
    const float* bc2 = (const float*)d_in[10];
    float* out = (float*)d_out;
    char* wsb = (char*)d_ws;

    const int N = in_sizes[0] / 64;
    const int E = in_sizes[1] / 2;
    const int Q = in_sizes[2] / 2;
    const int W = (N + 1) / 2;
    const int chunk = (E + HB - 1) / HB;

    // workspace layout (word offsets, 4B units); peak 20304128 words = 81.2 MB
    float* dis       = (float*)wsb;                              // 65536
    int*   offs      = (int*)wsb + 65536;                        // N+1
    int*   cursor    = (int*)wsb + 131584;
    int*   bsum      = (int*)wsb + 197120;                       // 256
    int*   cntCol    = (int*)wsb + 197376;                       // 65536
    float* buv       = (float*)wsb + 262912;                     // 256
    unsigned short* UVhi = (unsigned short*)((int*)wsb + 263168);  // 32768 us
    unsigned short* UVlo = (unsigned short*)((int*)wsb + 279552);
    unsigned short* W1hi = (unsigned short*)((int*)wsb + 295936);  // 8192 us
    unsigned short* W1lo = (unsigned short*)((int*)wsb + 300032);
    int*   srcSorted = (int*)wsb + 304128;                       // E
    unsigned short* agg2hi = (unsigned short*)((int*)wsb + 1104128);   // N*128 us
    unsigned short* agg2lo = (unsigned short*)((int*)wsb + 4304128);
    float* h1s       = (float*)wsb + 7504128;                    // N*128 f32
    unsigned short* agg1hi = (unsigned short*)((int*)wsb + 13904128);  // N*64 us
    unsigned short* agg1lo = (unsigned short*)((int*)wsb + 15504128);
    // hist partials live inside the (then-dead) h1s region
    unsigned int* hRow = (unsigned int*)wsb + 7504128;           // HB*W
    unsigned int* hCol = (unsigned int*)wsb + 10704128;
    float* U = h1s;                                              // over dead h1s
    float* V = (float*)wsb + 13904128;                           // over dead agg1 (+ext)

    const int* row  = ei;
    const int* col  = ei + E;
    const int* srcA = eli;
    const int* dstA = eli + Q;

    const int scanB = (N + 1023) / 1024;

    k_hist<<<HB, 256, 0, stream>>>(row, col, hRow, hCol, E, W, chunk);
    k_reduce<<<(W + 255) / 256, 256, 0, stream>>>(hRow, hCol, cntCol, dis, N, W);
    k_scan1<<<scanB, 256, 0, stream>>>(cntCol, offs, bsum, N);
    k_scan2<<<1, 256, 0, stream>>>(bsum, scanB);
    k_scan3<<<(N + 255) / 256, 256, 0, stream>>>(offs, cursor, bsum, N, E);
    k_fill<<<(E + 255) / 256, 256, 0, stream>>>(row, col, cursor, srcSorted, E);
    k_fold<<<161, 256, 0, stream>>>(W1, W2, Wc1, b2, bc1, UVhi, UVlo, W1hi, W1lo, buv);
    k_gather<4, true><<<((size_t)N * 16 + 255) / 256, 256, 0, stream>>>(
        x, offs, srcSorted, dis, agg1hi, agg1lo, N);
    k_mfma1<<<(N + 15) / 16, 256, 0, stream>>>(agg1hi, agg1lo, W1hi, W1lo, b1, dis, h1s, N);
    k_gather<5, false><<<((size_t)N * 32 + 255) / 256, 256, 0, stream>>>(
        h1s, offs, srcSorted, dis, agg2hi, agg2lo, N);
    k_mfmaUV<<<(N + 15) / 16, 256, 0, stream>>>(agg2hi, agg2lo, UVhi, UVlo, buv, U, V, N);
    k_head<<<(Q + 15) / 16, 256, 0, stream>>>(U, V, srcA, dstA, Wc2, bc2, out, Q);
}

// Round 6
// 333.411 us; speedup vs baseline: 7.1969x; 1.0912x over previous
//
#include <hip/hip_runtime.h>

// N=50000, E=800000, Q=200000, d_in=64, h=128
// CSR-by-dest gather convs; split-bf16 MFMA GEMMs (weights always split);
// gather-domain features (h1, agg2) quantized to plain bf16 to halve random-row
// traffic. Folded U/V head + gather-dot. No feature atomics anywhere.

#define HB 128  // histogram blocks

typedef __attribute__((ext_vector_type(8))) short short8;
typedef __attribute__((ext_vector_type(4))) float floatx4;

static __device__ __forceinline__ unsigned int f2bf(float v) {
    union { float f; unsigned int u; } c; c.f = v;
    unsigned int lsb = (c.u >> 16) & 1u;
    c.u += 0x7FFFu + lsb;                 // round-to-nearest-even
    return c.u >> 16;
}
static __device__ __forceinline__ float bf2f(unsigned int h) {
    union { float f; unsigned int u; } c; c.u = h << 16;
    return c.f;
}
static __device__ __forceinline__ void store_split4(float4 v,
                                                    unsigned short* hi,
                                                    unsigned short* lo) {
    unsigned int h0 = f2bf(v.x), h1 = f2bf(v.y), h2 = f2bf(v.z), h3 = f2bf(v.w);
    uint2 hw; hw.x = h0 | (h1 << 16); hw.y = h2 | (h3 << 16);
    unsigned int l0 = f2bf(v.x - bf2f(h0)), l1 = f2bf(v.y - bf2f(h1));
    unsigned int l2 = f2bf(v.z - bf2f(h2)), l3 = f2bf(v.w - bf2f(h3));
    uint2 lw; lw.x = l0 | (l1 << 16); lw.y = l2 | (l3 << 16);
    *(uint2*)hi = hw;
    *(uint2*)lo = lw;
}

// ---------- degree histogram (LDS-privatized, 16-bit packed) ----------
__global__ __launch_bounds__(256) void k_hist(const int* __restrict__ row,
                                              const int* __restrict__ col,
                                              unsigned int* __restrict__ hRow,
                                              unsigned int* __restrict__ hCol,
                                              int E, int W, int chunk) {
    __shared__ unsigned int lds[16384];
    int t = threadIdx.x, b = blockIdx.x;
    int e0 = b * chunk, e1 = min(E, e0 + chunk);
    for (int p = 0; p < 2; p++) {
        const int* idxArr = p ? col : row;
        unsigned int* outArr = p ? hCol : hRow;
        for (int base = 0; base < W; base += 16384) {
            int wcap = min(W - base, 16384);
            for (int i = t; i < wcap; i += 256) lds[i] = 0;
            __syncthreads();
            for (int e = e0 + t; e < e1; e += 256) {
                int idx = idxArr[e];
                int w = (idx >> 1) - base;
                if ((unsigned)w < (unsigned)wcap)
                    atomicAdd(&lds[w], 1u << ((idx & 1) * 16));
            }
            __syncthreads();
            for (int i = t; i < wcap; i += 256)
                outArr[(size_t)b * W + base + i] = lds[i];
            __syncthreads();
        }
    }
}

__global__ __launch_bounds__(256) void k_reduce(const unsigned int* __restrict__ hRow,
                                                const unsigned int* __restrict__ hCol,
                                                int* __restrict__ cntCol,
                                                float* __restrict__ dis,
                                                int N, int W) {
    int w = blockIdx.x * 256 + threadIdx.x;
    if (w >= W) return;
    unsigned int r0 = 0, r1 = 0, c0 = 0, c1 = 0;
#pragma unroll 8
    for (int b = 0; b < HB; b++) {
        unsigned int hr = hRow[(size_t)b * W + w];
        unsigned int hc = hCol[(size_t)b * W + w];
        r0 += hr & 0xFFFFu; r1 += hr >> 16;
        c0 += hc & 0xFFFFu; c1 += hc >> 16;
    }
    int n0 = 2 * w, n1 = 2 * w + 1;
    cntCol[n0] = (int)c0;
    dis[n0] = 1.0f / sqrtf((float)(r0 + 1));
    if (n1 < N) {
        cntCol[n1] = (int)c1;
        dis[n1] = 1.0f / sqrtf((float)(r1 + 1));
    }
}

// ---------- scan ----------
__global__ __launch_bounds__(256) void k_scan1(const int* __restrict__ cnt,
                                               int* __restrict__ offs,
                                               int* __restrict__ bsum, int N) {
    __shared__ int ts[256];
    int t = threadIdx.x;
    int base = blockIdx.x * 1024 + t * 4;
    int v0 = (base + 0 < N) ? cnt[base + 0] : 0;
    int v1 = (base + 1 < N) ? cnt[base + 1] : 0;
    int v2 = (base + 2 < N) ? cnt[base + 2] : 0;
    int v3 = (base + 3 < N) ? cnt[base + 3] : 0;
    int sum = v0 + v1 + v2 + v3;
    ts[t] = sum;
    __syncthreads();
    for (int off = 1; off < 256; off <<= 1) {
        int x = (t >= off) ? ts[t - off] : 0;
        __syncthreads();
        ts[t] += x;
        __syncthreads();
    }
    int e = ts[t] - sum;
    if (base + 0 < N) offs[base + 0] = e;
    if (base + 1 < N) offs[base + 1] = e + v0;
    if (base + 2 < N) offs[base + 2] = e + v0 + v1;
    if (base + 3 < N) offs[base + 3] = e + v0 + v1 + v2;
    if (t == 255) bsum[blockIdx.x] = ts[255];
}

__global__ __launch_bounds__(256) void k_scan2(int* __restrict__ bsum, int B) {
    __shared__ int ts[256];
    int t = threadIdx.x;
    int v = (t < B) ? bsum[t] : 0;
    ts[t] = v;
    __syncthreads();
    for (int off = 1; off < 256; off <<= 1) {
        int x = (t >= off) ? ts[t - off] : 0;
        __syncthreads();
        ts[t] += x;
        __syncthreads();
    }
    if (t < B) bsum[t] = ts[t] - v;
}

__global__ __launch_bounds__(256) void k_scan3(int* __restrict__ offs,
                                               int* __restrict__ cursor,
                                               const int* __restrict__ bsum,
                                               int N, int E) {
    int i = blockIdx.x * 256 + threadIdx.x;
    if (i < N) {
        int o = offs[i] + bsum[i >> 10];
        offs[i] = o;
        cursor[i] = o;
    }
    if (i == 0) offs[N] = E;
}

__global__ __launch_bounds__(256) void k_fill(const int* __restrict__ row,
                                              const int* __restrict__ col,
                                              int* __restrict__ cursor,
                                              int* __restrict__ srcSorted, int E) {
    int e = blockIdx.x * 256 + threadIdx.x;
    if (e < E) {
        int c = col[e];
        int pos = atomicAdd(&cursor[c], 1);
        srcSorted[pos] = row[e];
    }
}

// ---------- conv1 gather: fp32 x in, split-bf16 agg1 out (d=64) ----------
__global__ __launch_bounds__(256) void k_gather1(const float* __restrict__ s,
                                                 const int* __restrict__ offs,
                                                 const int* __restrict__ srcs,
                                                 const float* __restrict__ dis,
                                                 unsigned short* __restrict__ aggHi,
                                                 unsigned short* __restrict__ aggLo,
                                                 int N) {
    int tid = blockIdx.x * 256 + threadIdx.x;
    int node = tid >> 4;
    if (node >= N) return;
    int c4 = (tid & 15) * 4;
    int e = offs[node], eEnd = offs[node + 1];
    float dn = dis[node];
    float4 acc = *(const float4*)(s + (size_t)node * 64 + c4);
    acc.x *= dn; acc.y *= dn; acc.z *= dn; acc.w *= dn;
    int srcNext = (e < eEnd) ? srcs[e] : 0;
    float dNext = dis[srcNext];
    while (e < eEnd) {
        int src = srcNext;
        float dsrc = dNext;
        e++;
        srcNext = (e < eEnd) ? srcs[e] : 0;
        dNext = dis[srcNext];
        float4 v = *(const float4*)(s + (size_t)src * 64 + c4);
        acc.x += v.x * dsrc; acc.y += v.y * dsrc;
        acc.z += v.z * dsrc; acc.w += v.w * dsrc;
    }
    acc.x *= dn; acc.y *= dn; acc.z *= dn; acc.w *= dn;
    store_split4(acc, aggHi + (size_t)node * 64 + c4, aggLo + (size_t)node * 64 + c4);
}

// ---------- conv2 gather: bf16 h1 in, bf16 agg2 out (d=128) ----------
__global__ __launch_bounds__(256) void k_gather2(const unsigned short* __restrict__ s,
                                                 const int* __restrict__ offs,
                                                 const int* __restrict__ srcs,
                                                 const float* __restrict__ dis,
                                                 unsigned short* __restrict__ agg,
                                                 int N) {
    int tid = blockIdx.x * 256 + threadIdx.x;
    int node = tid >> 4;
    if (node >= N) return;
    int c8 = (tid & 15) * 8;  // bf16 element offset; 16 B per thread
    int e = offs[node], eEnd = offs[node + 1];
    float dn = dis[node];
    uint4 w = *(const uint4*)(s + (size_t)node * 128 + c8);
    float a0 = bf2f(w.x & 0xFFFF), a1 = bf2f(w.x >> 16);
    float a2 = bf2f(w.y & 0xFFFF), a3 = bf2f(w.y >> 16);
    float a4 = bf2f(w.z & 0xFFFF), a5 = bf2f(w.z >> 16);
    float a6 = bf2f(w.w & 0xFFFF), a7 = bf2f(w.w >> 16);
    int srcNext = (e < eEnd) ? srcs[e] : 0;
    while (e < eEnd) {
        int src = srcNext;
        e++;
        srcNext = (e < eEnd) ? srcs[e] : 0;
        uint4 v = *(const uint4*)(s + (size_t)src * 128 + c8);
        a0 += bf2f(v.x & 0xFFFF); a1 += bf2f(v.x >> 16);
        a2 += bf2f(v.y & 0xFFFF); a3 += bf2f(v.y >> 16);
        a4 += bf2f(v.z & 0xFFFF); a5 += bf2f(v.z >> 16);
        a6 += bf2f(v.w & 0xFFFF); a7 += bf2f(v.w >> 16);
    }
    uint4 o;
    o.x = f2bf(a0 * dn) | (f2bf(a1 * dn) << 16);
    o.y = f2bf(a2 * dn) | (f2bf(a3 * dn) << 16);
    o.z = f2bf(a4 * dn) | (f2bf(a5 * dn) << 16);
    o.w = f2bf(a6 * dn) | (f2bf(a7 * dn) << 16);
    *(uint4*)(agg + (size_t)node * 128 + c8) = o;
}

// ---------- fold + pack weights (split bf16, MFMA B-frag layout) ----------
__global__ __launch_bounds__(256) void k_fold(const float* __restrict__ W1,
                                              const float* __restrict__ W2,
                                              const float* __restrict__ Wc1,
                                              const float* __restrict__ b2,
                                              const float* __restrict__ bc1,
                                              unsigned short* __restrict__ UVhi,
                                              unsigned short* __restrict__ UVlo,
                                              unsigned short* __restrict__ W1hi,
                                              unsigned short* __restrict__ W1lo,
                                              float* __restrict__ buv) {
    __shared__ float w2row[128];
    int t = threadIdx.x, b = blockIdx.x;
    if (b < 128) {
        int k = b;
        int j = t & 127, half = t >> 7;
        int n = half * 128 + j;
        const float* wc = Wc1 + (size_t)half * 128 * 128 + j;
        if (t < 128) w2row[t] = W2[k * 128 + t];
        __syncthreads();
        float acc = 0.f;
#pragma unroll 8
        for (int m = 0; m < 128; m++) acc += w2row[m] * wc[(size_t)m * 128];
        int kstep = k >> 5, kl = k & 31, quad = kl >> 3, j8 = kl & 7;
        int nb = n >> 4, l = quad * 16 + (n & 15);
        int pidx = ((kstep * 16 + nb) * 64 + l) * 8 + j8;
        unsigned int h = f2bf(acc);
        UVhi[pidx] = (unsigned short)h;
        UVlo[pidx] = (unsigned short)f2bf(acc - bf2f(h));
    } else if (b == 128) {
        int j = t & 127, half = t >> 7;
        const float* wc = Wc1 + (size_t)half * 128 * 128 + j;
        float acc = half ? 0.f : bc1[j];
#pragma unroll 8
        for (int m = 0; m < 128; m++) acc += b2[m] * wc[(size_t)m * 128];
        buv[half * 128 + j] = acc;
    } else {
        int idx = (b - 129) * 256 + t;  // < 8192
        int k = idx >> 7, n = idx & 127;
        float v = W1[k * 128 + n];
        int kstep = k >> 5, kl = k & 31, quad = kl >> 3, j8 = kl & 7;
        int nb = n >> 4, l = quad * 16 + (n & 15);
        int pidx = ((kstep * 8 + nb) * 64 + l) * 8 + j8;
        unsigned int h = f2bf(v);
        W1hi[pidx] = (unsigned short)h;
        W1lo[pidx] = (unsigned short)f2bf(v - bf2f(h));
    }
}

// ---------- MFMA GEMM 1: h1b = bf16(relu(agg1 @ W1 + b1) * dis)  [K=64, 128 cols] ----------
__global__ __launch_bounds__(256) void k_mfma1(const unsigned short* __restrict__ Ahi,
                                               const unsigned short* __restrict__ Alo,
                                               const unsigned short* __restrict__ Bhi,
                                               const unsigned short* __restrict__ Blo,
                                               const float* __restrict__ b1,
                                               const float* __restrict__ dis,
                                               unsigned short* __restrict__ h1b, int N) {
    int lane = threadIdx.x & 63, wave = threadIdx.x >> 6;
    int mbase = blockIdx.x * 16;
    int ma = mbase + (lane & 15); if (ma >= N) ma = N - 1;
    int quad = lane >> 4;
    floatx4 acc[2] = {};
#pragma unroll
    for (int ks = 0; ks < 2; ks++) {
        short8 ahi = *(const short8*)(Ahi + (size_t)ma * 64 + ks * 32 + quad * 8);
        short8 alo = *(const short8*)(Alo + (size_t)ma * 64 + ks * 32 + quad * 8);
#pragma unroll
        for (int nt = 0; nt < 2; nt++) {
            int nb = wave * 2 + nt;
            short8 bhi = *(const short8*)(Bhi + ((ks * 8 + nb) * 64 + lane) * 8);
            short8 blo = *(const short8*)(Blo + ((ks * 8 + nb) * 64 + lane) * 8);
            acc[nt] = __builtin_amdgcn_mfma_f32_16x16x32_bf16(ahi, bhi, acc[nt], 0, 0, 0);
            acc[nt] = __builtin_amdgcn_mfma_f32_16x16x32_bf16(ahi, blo, acc[nt], 0, 0, 0);
            acc[nt] = __builtin_amdgcn_mfma_f32_16x16x32_bf16(alo, bhi, acc[nt], 0, 0, 0);
        }
    }
    int md = mbase + quad * 4;
#pragma unroll
    for (int nt = 0; nt < 2; nt++) {
        int n0 = (wave * 2 + nt) * 16 + (lane & 15);
        float bias = b1[n0];
#pragma unroll
        for (int r = 0; r < 4; r++) {
            int node = md + r;
            if (node < N)
                h1b[(size_t)node * 128 + n0] =
                    (unsigned short)f2bf(fmaxf(acc[nt][r] + bias, 0.f) * dis[node]);
        }
    }
}

// ---------- MFMA GEMM UV: [U|V] = agg2b @ Wfull + buv  [K=128, 256 cols, A bf16] ----------
__global__ __launch_bounds__(256) void k_mfmaUV(const unsigned short* __restrict__ A,
                                                const unsigned short* __restrict__ Bhi,
                                                const unsigned short* __restrict__ Blo,
                                                const float* __restrict__ buv,
                                                float* __restrict__ U,
                                                float* __restrict__ V, int N) {
    int lane = threadIdx.x & 63, wave = threadIdx.x >> 6;
    int mbase = blockIdx.x * 16;
    int ma = mbase + (lane & 15); if (ma >= N) ma = N - 1;
    int quad = lane >> 4;
    floatx4 acc[4] = {};
#pragma unroll
    for (int ks = 0; ks < 4; ks++) {
        short8 a = *(const short8*)(A + (size_t)ma * 128 + ks * 32 + quad * 8);
#pragma unroll
        for (int nt = 0; nt < 4; nt++) {
            int nb = wave * 4 + nt;
            short8 bhi = *(const short8*)(Bhi + ((ks * 16 + nb) * 64 + lane) * 8);
            short8 blo = *(const short8*)(Blo + ((ks * 16 + nb) * 64 + lane) * 8);
            acc[nt] = __builtin_amdgcn_mfma_f32_16x16x32_bf16(a, bhi, acc[nt], 0, 0, 0);
            acc[nt] = __builtin_amdgcn_mfma_f32_16x16x32_bf16(a, blo, acc[nt], 0, 0, 0);
        }
    }
    int md = mbase + quad * 4;
#pragma unroll
    for (int nt = 0; nt < 4; nt++) {
        int n0 = wave * 64 + nt * 16 + (lane & 15);
        float bias = buv[n0];
        float* dst = (n0 < 128) ? U : V;
        int cc = n0 & 127;
#pragma unroll
        for (int r = 0; r < 4; r++) {
            int node = md + r;
            if (node < N)
                dst[(size_t)node * 128 + cc] = acc[nt][r] + bias;
        }
    }
}

// ---------- head: out[q] = relu(U[src]+V[dst]) . Wc2 + bc2 ----------
__global__ __launch_bounds__(256) void k_head(const float* __restrict__ U,
                                              const float* __restrict__ V,
                                              const int* __restrict__ srcA,
                                              const int* __restrict__ dstA,
                                              const float* __restrict__ Wc2,
                                              const float* __restrict__ bc2,
                                              float* __restrict__ out, int Q) {
    int t = threadIdx.x;
    int q = blockIdx.x * 16 + (t >> 4);
    if (q >= Q) return;
    int l = t & 15;
    int s = srcA[q], d = dstA[q];
    const float4* u = (const float4*)(U + (size_t)s * 128 + l * 8);
    const float4* v = (const float4*)(V + (size_t)d * 128 + l * 8);
    const float4* w = (const float4*)(Wc2 + l * 8);
    float4 u0 = u[0], u1 = u[1];
    float4 v0 = v[0], v1 = v[1];
    float4 w0 = w[0], w1 = w[1];
    float acc = 0.f, z;
    z = fmaxf(u0.x + v0.x, 0.f); acc += z * w0.x;
    z = fmaxf(u0.y + v0.y, 0.f); acc += z * w0.y;
    z = fmaxf(u0.z + v0.z, 0.f); acc += z * w0.z;
    z = fmaxf(u0.w + v0.w, 0.f); acc += z * w0.w;
    z = fmaxf(u1.x + v1.x, 0.f); acc += z * w1.x;
    z = fmaxf(u1.y + v1.y, 0.f); acc += z * w1.y;
    z = fmaxf(u1.z + v1.z, 0.f); acc += z * w1.z;
    z = fmaxf(u1.w + v1.w, 0.f); acc += z * w1.w;
    acc += __shfl_xor(acc, 1);
    acc += __shfl_xor(acc, 2);
    acc += __shfl_xor(acc, 4);
    acc += __shfl_xor(acc, 8);
    if (l == 0) out[q] = acc + bc2[0];
}

extern "C" void kernel_launch(void* const* d_in, const int* in_sizes, int n_in,
                              void* d_out, int out_size, void* d_ws, size_t ws_size,
                              hipStream_t stream) {
    const float* x   = (const float*)d_in[0];
    const int*   ei  = (const int*)d_in[1];
    const int*   eli = (const int*)d_in[2];
    const float* W1  = (const float*)d_in[3];
    const float* b1  = (const float*)d_in[4];
    const float* W2  = (const float*)d_in[5];
    const float* b2  = (const float*)d_in[6];
    const float* Wc1 = (const float*)d_in[7];
    const float* bc1 = (const float*)d_in[8];
    const float* Wc2 = (const float*)d_in[9];
    const float* bc2 = (const float*)d_in[10];
    float* out = (float*)d_out;
    char* wsb = (char*)d_ws;

    const int N = in_sizes[0] / 64;
    const int E = in_sizes[1] / 2;
    const int Q = in_sizes[2] / 2;
    const int W = (N + 1) / 2;
    const int chunk = (E + HB - 1) / HB;

    // workspace layout (word offsets, 4B units); peak 17104128 words = 68.4 MB
    float* dis       = (float*)wsb;                                // 65536
    int*   offs      = (int*)wsb + 65536;                          // N+1
    int*   cursor    = (int*)wsb + 131584;                         // N
    int*   bsum      = (int*)wsb + 197120;                         // 256
    int*   cntCol    = (int*)wsb + 197376;                         // 65536
    float* buv       = (float*)wsb + 262912;                       // 256
    unsigned short* UVhi = (unsigned short*)((int*)wsb + 263168);  // 32768 us
    unsigned short* UVlo = (unsigned short*)((int*)wsb + 279552);
    unsigned short* W1hi = (unsigned short*)((int*)wsb + 295936);  // 8192 us
    unsigned short* W1lo = (unsigned short*)((int*)wsb + 300032);
    int*   srcSorted = (int*)wsb + 304128;                         // E -> 1104128
    // V spans [1104128, 7504128) and overlays dead agg1 + h1b at mfmaUV time
    float* V = (float*)wsb + 1104128;
    unsigned short* agg1hi = (unsigned short*)((int*)wsb + 1104128);  // N*64 us
    unsigned short* agg1lo = (unsigned short*)((int*)wsb + 2704128);
    unsigned short* h1b    = (unsigned short*)((int*)wsb + 4304128);  // N*128 us
    unsigned short* agg2b  = (unsigned short*)((int*)wsb + 7504128);  // N*128 us -> 10704128
    // U spans [10704128, 17104128) and overlays dead hist partials
    float* U = (float*)wsb + 10704128;
    unsigned int* hRow = (unsigned int*)wsb + 10704128;            // HB*W -> 13904128
    unsigned int* hCol = (unsigned int*)wsb + 13904128;            // HB*W -> 17104128

    const int* row  = ei;
    const int* col  = ei + E;
    const int* srcA = eli;
    const int* dstA = eli + Q;

    const int scanB = (N + 1023) / 1024;

    k_hist<<<HB, 256, 0, stream>>>(row, col, hRow, hCol, E, W, chunk);
    k_reduce<<<(W + 255) / 256, 256, 0, stream>>>(hRow, hCol, cntCol, dis, N, W);
    k_scan1<<<scanB, 256, 0, stream>>>(cntCol, offs, bsum, N);
    k_scan2<<<1, 256, 0, stream>>>(bsum, scanB);
    k_scan3<<<(N + 255) / 256, 256, 0, stream>>>(offs, cursor, bsum, N, E);
    k_fill<<<(E + 255) / 256, 256, 0, stream>>>(row, col, cursor, srcSorted, E);
    k_fold<<<161, 256, 0, stream>>>(W1, W2, Wc1, b2, bc1, UVhi, UVlo, W1hi, W1lo, buv);
    k_gather1<<<((size_t)N * 16 + 255) / 256, 256, 0, stream>>>(
        x, offs, srcSorted, dis, agg1hi, agg1lo, N);
    k_mfma1<<<(N + 15) / 16, 256, 0, stream>>>(agg1hi, agg1lo, W1hi, W1lo, b1, dis, h1b, N);
    k_gather2<<<((size_t)N * 16 + 255) / 256, 256, 0, stream>>>(
        h1b, offs, srcSorted, dis, agg2b, N);
    k_mfmaUV<<<(N + 15) / 16, 256, 0, stream>>>(agg2b, UVhi, UVlo, buv, U, V, N);
    k_head<<<(Q + 15) / 16, 256, 0, stream>>>(U, V, srcA, dstA, Wc2, bc2, out, Q);
}